// Round 8
// baseline (5324.427 us; speedup 1.0000x reference)
//
#include <hip/hip_runtime.h>
#include <math.h>

// Problem constants: B=8, S=224, P=14, D=512, L=6, NPS=16, N=256, G=5, H=2048, iters=12
#define L6 6

typedef __attribute__((ext_vector_type(8))) short bf16x8;   // 8 bf16 in 4 VGPRs
typedef __attribute__((ext_vector_type(4))) float f32x4;    // MFMA accum

#define SH_W_GRP   2097152ull   // 512*2048 hi/lo bf16 (both W1 and W2)
#define SH_A_GRP   2097152ull   // 2048 tok * 512 d hi/lo
#define SH_A_TDOFF 10485760ull  // Atd offset inside Apk (5 groups)

// Exact gelu (erff): r10-proven epilogue.
__device__ __forceinline__ float gelu_exact(float x) {
  return 0.5f * x * (1.0f + erff(x * 0.70710678118654752f));
}

__device__ __forceinline__ unsigned short bf16_rn(float x) {
  unsigned u = __float_as_uint(x);
  unsigned r = u + 0x7FFFu + ((u >> 16) & 1u);
  return (unsigned short)(r >> 16);
}
__device__ __forceinline__ float bf16_f(unsigned short h) {
  return __uint_as_float(((unsigned)h) << 16);
}
__device__ __forceinline__ void split2(float x, unsigned short* h, unsigned short* l) {
  unsigned short hh = bf16_rn(x);
  *h = hh;
  *l = bf16_rn(x - bf16_f(hh));
}
__device__ __forceinline__ int4 pack8(const unsigned short* v) {
  return make_int4((int)((unsigned)v[0] | ((unsigned)v[1] << 16)),
                   (int)((unsigned)v[2] | ((unsigned)v[3] << 16)),
                   (int)((unsigned)v[4] | ((unsigned)v[5] << 16)),
                   (int)((unsigned)v[6] | ((unsigned)v[7] << 16)));
}

__device__ __forceinline__ void gload16(const void* g, void* l) {
  __builtin_amdgcn_global_load_lds(
      (const __attribute__((address_space(1))) void*)g,
      (__attribute__((address_space(3))) void*)l, 16, 0, 0);
}

// ---------------------------------------------------------------------------
// Patch embedding
// ---------------------------------------------------------------------------
__global__ __launch_bounds__(256) void patch_embed(
    const float* __restrict__ img, const float* __restrict__ Wp,
    const float* __restrict__ bp, float* __restrict__ tokens)
{
  __shared__ float xs[588];
  const int bn = blockIdx.x;
  const int b = bn >> 8, n = bn & 255;
  const int i = n >> 4, j = n & 15;
  for (int k = threadIdx.x; k < 588; k += 256) {
    int c = k % 3;
    int t = k / 3;
    int pc = t % 14;
    int pr = t / 14;
    xs[k] = img[(((size_t)(b * 3 + c) * 224) + (i * 14 + pr)) * 224 + (j * 14 + pc)];
  }
  __syncthreads();
  const int d0 = threadIdx.x, d1 = threadIdx.x + 256;
  float a0 = 0.f, a1 = 0.f;
  for (int k = 0; k < 588; ++k) {
    float x = xs[k];
    a0 = fmaf(x, Wp[(size_t)k * 512 + d0], a0);
    a1 = fmaf(x, Wp[(size_t)k * 512 + d1], a1);
  }
  tokens[(size_t)bn * 512 + d0] = a0 + bp[d0];
  tokens[(size_t)bn * 512 + d1] = a1 + bp[d1];
}

// ---------------------------------------------------------------------------
__global__ __launch_bounds__(256) void init_lv_kernel(
    const float* __restrict__ initl, float* __restrict__ lv)
{
  int f = blockIdx.x * 256 + threadIdx.x;
  int d4 = f & 127;
  int l = (f >> 15) % 6;
  float4 v = *(const float4*)(initl + (size_t)l * 512 + d4 * 4);
  *(float4*)(lv + (size_t)f * 4) = v;
}

// ---------------------------------------------------------------------------
// Startup norms: invn[bl][n] = 1/max(||lv[bl,n,:]||, 1e-12). One-shot;
// steady-state values produced by combine3's fused wave-reduce.
// ---------------------------------------------------------------------------
__global__ __launch_bounds__(256) void norm0_k(
    const float* __restrict__ lv, float* __restrict__ invn)
{
  int bl = blockIdx.x;
  int n = threadIdx.x;
  const float* row = lv + ((size_t)bl * 256 + n) * 512;
  float ss = 0.f;
  for (int k = 0; k < 512; k += 4) {
    float4 v = *(const float4*)(row + k);
    ss = fmaf(v.x, v.x, ss);
    ss = fmaf(v.y, v.y, ss);
    ss = fmaf(v.z, v.z, ss);
    ss = fmaf(v.w, v.w, ss);
  }
  invn[(size_t)bl * 256 + n] = 1.0f / fmaxf(sqrtf(ss), 1e-12f);
}

// ---------------------------------------------------------------------------
// Pack weights fp32 [G][K][N] -> hi/lo bf16 fragment-image.
// ---------------------------------------------------------------------------
__global__ __launch_bounds__(256) void pack_w(
    const float* __restrict__ src, short* __restrict__ dst, int KT, int NT)
{
  int sidx = blockIdx.x * 256 + threadIdx.x;
  int slot = sidx & 511;
  int blk = sidx >> 9;
  int kt = blk % KT;
  int rest = blk / KT;
  int nt = rest % NT;
  int g = rest / NT;
  int f = slot >> 6, lane = slot & 63;
  int N = NT * 128, K = KT * 32;
  int n = nt * 128 + f * 16 + (lane & 15);
  int k0 = kt * 32 + (lane >> 4) * 8;
  const float* s = src + ((size_t)g * K + k0) * N + n;
  unsigned short hi[8], lo[8];
#pragma unroll
  for (int j = 0; j < 8; ++j) split2(s[(size_t)j * N], &hi[j], &lo[j]);
  short* d = dst + (size_t)blk * 8192 + slot * 8;
  *(int4*)d = pack8(hi);
  *(int4*)(d + 4096) = pack8(lo);
}

// ---------------------------------------------------------------------------
// Startup A-pack (steady-state fused into combine3).
// ---------------------------------------------------------------------------
__global__ __launch_bounds__(256) void pack_A(
    const float* __restrict__ lv, const float* __restrict__ pos,
    short* __restrict__ Abu, short* __restrict__ Atd)
{
  const int bx = blockIdx.x;              // 0..1279
  const int lg = bx >> 8, mt = (bx >> 4) & 15, kt = bx & 15;
  const size_t blk = (size_t)bx * 8192;
#pragma unroll
  for (int ss = 0; ss < 2; ++ss) {
    int s = threadIdx.x + ss * 256;
    int f = s >> 6, l = s & 63;
    int m = mt * 128 + (f << 4) + (l & 15);
    int b = m >> 8, n = m & 255;
    int d = kt * 32 + ((l >> 4) << 3);
    const float* pbu = lv + ((size_t)(b * L6 + lg) * 256 + n) * 512 + d;
    const float* ptd = lv + ((size_t)(b * L6 + lg + 1) * 256 + n) * 512 + d;
    const float* pp = pos + (size_t)n * 512 + d;
    float4 u0 = *(const float4*)pbu;
    float4 u1 = *(const float4*)(pbu + 4);
    float xv[8] = {u0.x, u0.y, u0.z, u0.w, u1.x, u1.y, u1.z, u1.w};
    unsigned short hi[8], lo[8];
#pragma unroll
    for (int j = 0; j < 8; ++j) split2(xv[j], &hi[j], &lo[j]);
    *(int4*)(Abu + blk + s * 8) = pack8(hi);
    *(int4*)(Abu + blk + 4096 + s * 8) = pack8(lo);
    float4 v0 = *(const float4*)ptd;
    float4 v1 = *(const float4*)(ptd + 4);
    float4 p0 = *(const float4*)pp;
    float4 p1 = *(const float4*)(pp + 4);
    float yv[8] = {v0.x + p0.x, v0.y + p0.y, v0.z + p0.z, v0.w + p0.w,
                   v1.x + p1.x, v1.y + p1.y, v1.z + p1.z, v1.w + p1.w};
#pragma unroll
    for (int j = 0; j < 8; ++j) split2(yv[j], &hi[j], &lo[j]);
    *(int4*)(Atd + blk + s * 8) = pack8(hi);
    *(int4*)(Atd + blk + 4096 + s * 8) = pack8(lo);
  }
}

// ---------------------------------------------------------------------------
// FF1 r8: LDS-FREE flat GEMM. Operands live in fragment-image order
// (frag*512 + lane*8 shorts), so each wave loads its A/B fragments
// global->VGPR directly (global_load_dwordx4, 1KB/wave, coalesced).
// No __shared__, NO barriers in the K-loop -> waves slip freely and
// TLP hides load latency (the r2 structure ran pipes serially:
// MFMA 31 + LDS 26 + VALU 23 + VMEM 17 ~= 97us of its 109us).
// Same fragment values, same MFMA order per acc -> bit-identical.
// ---------------------------------------------------------------------------
__global__ __launch_bounds__(256, 3) void ff1_k(
    const short* __restrict__ Wa, const short* __restrict__ Ap,
    const float* __restrict__ b1, short* __restrict__ hpk)
{
  const int per_x = gridDim.x >> 3;
  const int gid = (blockIdx.x & 7) * per_x + (blockIdx.x >> 3);
  const int tt = gid & 15;
  const int tile = gid >> 4;
  const int ht = tile & 15;
  const int z = tile >> 4;
  const int tid = threadIdx.x, lane = tid & 63, w = tid >> 6;
  const int wm = (w >> 1) * 64, wn = (w & 1) * 64;
  // (wm>>4)*512 = wm*32 = wm<<5 : this wave's fragment base in the image
  const short* ga = Wa + (size_t)(z * 16 + ht) * 16 * 8192 + (wm << 5) + lane * 8;
  const short* gb = Ap + (size_t)(z * 16 + tt) * 16 * 8192 + (wn << 5) + lane * 8;

  f32x4 acc[4][4];
#pragma unroll
  for (int i = 0; i < 4; ++i)
#pragma unroll
    for (int j = 0; j < 4; ++j) acc[i][j] = (f32x4)(0.0f);

  for (int kt = 0; kt < 16; ++kt) {
    const short* pa = ga + (size_t)kt * 8192;
    const short* pb = gb + (size_t)kt * 8192;
    bf16x8 ah[4], al[4], bh[4], bl[4];
#pragma unroll
    for (int i = 0; i < 4; ++i) {
      ah[i] = *(const bf16x8*)(pa + i * 512);
      al[i] = *(const bf16x8*)(pa + 4096 + i * 512);
    }
#pragma unroll
    for (int j = 0; j < 4; ++j) {
      bh[j] = *(const bf16x8*)(pb + j * 512);
      bl[j] = *(const bf16x8*)(pb + 4096 + j * 512);
    }
    // pass 1: A_hi * B_hi
#pragma unroll
    for (int j = 0; j < 4; ++j)
#pragma unroll
      for (int i = 0; i < 4; ++i)
        acc[i][j] = __builtin_amdgcn_mfma_f32_16x16x32_bf16(
            ah[i], bh[j], acc[i][j], 0, 0, 0);
    // pass 2: A_lo * B_hi
#pragma unroll
    for (int j = 0; j < 4; ++j)
#pragma unroll
      for (int i = 0; i < 4; ++i)
        acc[i][j] = __builtin_amdgcn_mfma_f32_16x16x32_bf16(
            al[i], bh[j], acc[i][j], 0, 0, 0);
    // pass 3: A_hi * B_lo
#pragma unroll
    for (int j = 0; j < 4; ++j)
#pragma unroll
      for (int i = 0; i < 4; ++i)
        acc[i][j] = __builtin_amdgcn_mfma_f32_16x16x32_bf16(
            ah[i], bl[j], acc[i][j], 0, 0, 0);
  }

  const int q = lane >> 4, t = lane & 15;
  const float* b1g = b1 + (size_t)z * 2048;
#pragma unroll
  for (int i = 0; i < 4; ++i) {
    int Hb = ht * 128 + wm + i * 16 + q * 4;
    float4 bv = *(const float4*)(b1g + Hb);
    float bb[4] = {bv.x, bv.y, bv.z, bv.w};
    int kt2 = Hb >> 5;
    int g2 = (Hb >> 3) & 3;
    int jb = Hb & 7;                       // 0 or 4
    size_t blkbase = ((size_t)(z * 16 + tt) * 64 + kt2) * 8192;
#pragma unroll
    for (int j = 0; j < 4; ++j) {
      int f2 = (wn >> 4) + j;
      size_t off = blkbase + (size_t)(f2 * 64 + g2 * 16 + t) * 8 + jb;
      unsigned short hi[4], lo[4];
#pragma unroll
      for (int r = 0; r < 4; ++r) {
        float x = gelu_exact(acc[i][j][r] + bb[r]);
        split2(x, &hi[r], &lo[r]);
      }
      *(uint2*)(hpk + off) =
          make_uint2((unsigned)hi[0] | ((unsigned)hi[1] << 16),
                     (unsigned)hi[2] | ((unsigned)hi[3] << 16));
      *(uint2*)(hpk + off + 4096) =
          make_uint2((unsigned)lo[0] | ((unsigned)lo[1] << 16),
                     (unsigned)lo[2] | ((unsigned)lo[3] << 16));
    }
  }
}

// ---------------------------------------------------------------------------
// Attention r7: MFMA Gram with norm table (unchanged from r7: 4731us best).
// ---------------------------------------------------------------------------
__global__ __launch_bounds__(256, 3) void attn_k(
    const float* __restrict__ lv, const short* __restrict__ Apk,
    const float* __restrict__ invn, float* __restrict__ attnb)
{
  __shared__ __align__(16) short Bhi[8192];   // 16 frags x 64 lanes x 8
  __shared__ __align__(16) short Blo[8192];
  __shared__ float scL[256];
  __shared__ float red[32][4];
  const int a = blockIdx.x;
  const int s = a >> 3;
  const int b = a & 7;                 // batch == XCD group
  const int l = s >> 3;                // level 0..5
  const int bl = b * 6 + l;
  const int i0 = (s & 7) * 32;
  const float* base = lv + (size_t)bl * 131072;
  const int tid = threadIdx.x, lane = tid & 63, w = tid >> 6;
  const int q = lane >> 4, c = lane & 15;

  scL[tid] = invn[(size_t)bl * 256 + tid];   // one row scale per thread

  f32x4 acc[2][4];
#pragma unroll
  for (int i = 0; i < 2; ++i)
#pragma unroll
    for (int j = 0; j < 4; ++j) acc[i][j] = (f32x4)(0.0f);

  // Apk bu-image sub-blocks for this (b,l): tokens n 0..127 -> tile 2b,
  // n 128..255 -> tile 2b+1. Valid only for l<5.
  const short* src0 = Apk + ((size_t)(l * 16 + 2 * b) * 16) * 8192;
  const short* src1 = Apk + ((size_t)(l * 16 + 2 * b + 1) * 16) * 8192;

  for (int kt = 0; kt < 16; ++kt) {
    __syncthreads();                    // prev step's LDS reads done
    if (l < 5) {
      const char* p0 = (const char*)(src0 + (size_t)kt * 8192);
      const char* p1 = (const char*)(src1 + (size_t)kt * 8192);
      gload16(p0 + tid * 16,         (char*)Bhi + tid * 16);
      gload16(p0 + 4096 + tid * 16,  (char*)Bhi + 4096 + tid * 16);
      gload16(p0 + 8192 + tid * 16,  (char*)Blo + tid * 16);
      gload16(p0 + 12288 + tid * 16, (char*)Blo + 4096 + tid * 16);
      gload16(p1 + tid * 16,         (char*)Bhi + 8192 + tid * 16);
      gload16(p1 + 4096 + tid * 16,  (char*)Bhi + 12288 + tid * 16);
      gload16(p1 + 8192 + tid * 16,  (char*)Blo + 8192 + tid * 16);
      gload16(p1 + 12288 + tid * 16, (char*)Blo + 12288 + tid * 16);
    } else {
      const int k0 = kt * 32;
#pragma unroll
      for (int it = 0; it < 8; ++it) {
        int f = it * 256 + tid;
        int j = f >> 3, c4 = f & 7;
        float4 v = *(const float4*)(base + (size_t)j * 512 + k0 + c4 * 4);
        unsigned short hi[4], lo[4];
        split2(v.x, &hi[0], &lo[0]);
        split2(v.y, &hi[1], &lo[1]);
        split2(v.z, &hi[2], &lo[2]);
        split2(v.w, &hi[3], &lo[3]);
        int fg = j >> 4;
        int la = (c4 >> 1) * 16 + (j & 15);
        int half = (c4 & 1) * 4;
        *(uint2*)&Bhi[fg * 512 + la * 8 + half] =
            make_uint2((unsigned)hi[0] | ((unsigned)hi[1] << 16),
                       (unsigned)hi[2] | ((unsigned)hi[3] << 16));
        *(uint2*)&Blo[fg * 512 + la * 8 + half] =
            make_uint2((unsigned)lo[0] | ((unsigned)lo[1] << 16),
                       (unsigned)lo[2] | ((unsigned)lo[3] << 16));
      }
    }
    __syncthreads();                    // staging complete
    bf16x8 ah[2], al[2], bh[4], blv[4];
#pragma unroll
    for (int i = 0; i < 2; ++i) {
      int fg = (i0 >> 4) + i;
      ah[i] = *(const bf16x8*)&Bhi[fg * 512 + lane * 8];
      al[i] = *(const bf16x8*)&Blo[fg * 512 + lane * 8];
    }
#pragma unroll
    for (int j = 0; j < 4; ++j) {
      int fg = w * 4 + j;
      bh[j] = *(const bf16x8*)&Bhi[fg * 512 + lane * 8];
      blv[j] = *(const bf16x8*)&Blo[fg * 512 + lane * 8];
    }
#pragma unroll
    for (int j = 0; j < 4; ++j)
#pragma unroll
      for (int i = 0; i < 2; ++i)
        acc[i][j] = __builtin_amdgcn_mfma_f32_16x16x32_bf16(
            ah[i], bh[j], acc[i][j], 0, 0, 0);
#pragma unroll
    for (int j = 0; j < 4; ++j)
#pragma unroll
      for (int i = 0; i < 2; ++i)
        acc[i][j] = __builtin_amdgcn_mfma_f32_16x16x32_bf16(
            al[i], bh[j], acc[i][j], 0, 0, 0);
#pragma unroll
    for (int j = 0; j < 4; ++j)
#pragma unroll
      for (int i = 0; i < 2; ++i)
        acc[i][j] = __builtin_amdgcn_mfma_f32_16x16x32_bf16(
            ah[i], blv[j], acc[i][j], 0, 0, 0);
  }
  __syncthreads();                      // scL writes visible (also from loop)

  const float rs = 0.04419417382415922f;  // 512^-0.5
  // scale + diag; value at (ai,bj,r): i = i0+ai*16+q*4+r, j = w*64+bj*16+c
#pragma unroll
  for (int ai = 0; ai < 2; ++ai)
#pragma unroll
    for (int bj = 0; bj < 4; ++bj)
#pragma unroll
      for (int r = 0; r < 4; ++r) {
        int i = i0 + ai * 16 + q * 4 + r;
        int j = w * 64 + bj * 16 + c;
        float sv = acc[ai][bj][r] * scL[j] * rs;
        if (j == i) sv = -0.0005f;
        acc[ai][bj][r] = sv;
      }
  // wave-local row max (over this wave's 64 j), then cross-wave via red
  float mx[2][4];
#pragma unroll
  for (int ai = 0; ai < 2; ++ai)
#pragma unroll
    for (int r = 0; r < 4; ++r) {
      float m = fmaxf(fmaxf(acc[ai][0][r], acc[ai][1][r]),
                      fmaxf(acc[ai][2][r], acc[ai][3][r]));
      m = fmaxf(m, __shfl_xor(m, 1));
      m = fmaxf(m, __shfl_xor(m, 2));
      m = fmaxf(m, __shfl_xor(m, 4));
      m = fmaxf(m, __shfl_xor(m, 8));
      mx[ai][r] = m;
    }
  if (c == 0) {
#pragma unroll
    for (int ai = 0; ai < 2; ++ai)
#pragma unroll
      for (int r = 0; r < 4; ++r) red[ai * 16 + q * 4 + r][w] = mx[ai][r];
  }
  __syncthreads();
#pragma unroll
  for (int ai = 0; ai < 2; ++ai)
#pragma unroll
    for (int r = 0; r < 4; ++r) {
      int row = ai * 16 + q * 4 + r;
      mx[ai][r] = fmaxf(fmaxf(red[row][0], red[row][1]),
                        fmaxf(red[row][2], red[row][3]));
    }
  __syncthreads();                      // before red reuse for sums
  float sm[2][4];
#pragma unroll
  for (int ai = 0; ai < 2; ++ai)
#pragma unroll
    for (int r = 0; r < 4; ++r) {
      float t = 0.f;
#pragma unroll
      for (int bj = 0; bj < 4; ++bj) {
        float e = expf(acc[ai][bj][r] - mx[ai][r]);
        acc[ai][bj][r] = e;
        t += e;
      }
      t += __shfl_xor(t, 1);
      t += __shfl_xor(t, 2);
      t += __shfl_xor(t, 4);
      t += __shfl_xor(t, 8);
      sm[ai][r] = t;
    }
  if (c == 0) {
#pragma unroll
    for (int ai = 0; ai < 2; ++ai)
#pragma unroll
      for (int r = 0; r < 4; ++r) red[ai * 16 + q * 4 + r][w] = sm[ai][r];
  }
  __syncthreads();
  float* ob = attnb + (size_t)bl * 65536;
#pragma unroll
  for (int ai = 0; ai < 2; ++ai)
#pragma unroll
    for (int r = 0; r < 4; ++r) {
      int row = ai * 16 + q * 4 + r;
      float S = red[row][0] + red[row][1] + red[row][2] + red[row][3];
      float inv = 1.0f / S;
      int i = i0 + row;
#pragma unroll
      for (int bj = 0; bj < 4; ++bj) {
        int j = w * 64 + bj * 16 + c;
        ob[(size_t)i * 256 + j] = acc[ai][bj][r] * inv;
      }
    }
}

// ---------------------------------------------------------------------------
// Consensus: accum += attnb @ lv (pure RMW). Grid 768, XCD-grouped by bl.
// ---------------------------------------------------------------------------
__global__ __launch_bounds__(256) void cons_k(
    const float* __restrict__ attnb, const float* __restrict__ lv,
    float* __restrict__ accum)
{
  __shared__ __align__(16) char smemraw[25088];
  const int a = blockIdx.x;
  const int s = a >> 3;
  const int bl = (a & 7) * 6 + (s >> 4);
  const int tile = s & 15;
  int it0 = (tile >> 2) * 64;
  int dt0 = (tile & 3) * 128;
  const float* A = attnb + (size_t)bl * 65536;
  const float* Bm = lv + (size_t)bl * 131072;
  float (*Ast)[68] = (float(*)[68])smemraw;
  float (*Bs)[128] = (float(*)[128])(smemraw + 8704);
  const int tid = threadIdx.x;
  const int ty = tid >> 4, tx = tid & 15;
  float acc[4][8];
#pragma unroll
  for (int i = 0; i < 4; ++i)
#pragma unroll
    for (int j = 0; j < 8; ++j) acc[i][j] = 0.f;

  for (int k0 = 0; k0 < 256; k0 += 32) {
#pragma unroll
    for (int it = 0; it < 2; ++it) {
      int f = it * 256 + tid;
      int r = f >> 3, c4 = f & 7;
      float4 v = *(const float4*)(A + (size_t)(it0 + r) * 256 + k0 + c4 * 4);
      Ast[c4 * 4 + 0][r] = v.x;
      Ast[c4 * 4 + 1][r] = v.y;
      Ast[c4 * 4 + 2][r] = v.z;
      Ast[c4 * 4 + 3][r] = v.w;
    }
#pragma unroll
    for (int it = 0; it < 4; ++it) {
      int kr = (tid >> 5) + it * 8;
      int c4 = tid & 31;
      *(float4*)&Bs[kr][c4 * 4] =
          *(const float4*)(Bm + (size_t)(k0 + kr) * 512 + dt0 + c4 * 4);
    }
    __syncthreads();
#pragma unroll 8
    for (int k = 0; k < 32; ++k) {
      float4 av = *(const float4*)&Ast[k][ty * 4];
      float4 b0 = *(const float4*)&Bs[k][tx * 4];
      float4 b1 = *(const float4*)&Bs[k][64 + tx * 4];
      float avv[4] = {av.x, av.y, av.z, av.w};
      float bv[8] = {b0.x, b0.y, b0.z, b0.w, b1.x, b1.y, b1.z, b1.w};
#pragma unroll
      for (int i = 0; i < 4; ++i)
#pragma unroll
        for (int j = 0; j < 8; ++j)
          acc[i][j] = fmaf(avv[i], bv[j], acc[i][j]);
    }
    __syncthreads();
  }
#pragma unroll
  for (int ii = 0; ii < 4; ++ii) {
    int i = it0 + ty * 4 + ii;
    float* arow = accum + (size_t)bl * 131072 + (size_t)i * 512 + dt0;
#pragma unroll
    for (int j = 0; j < 4; ++j) arow[tx * 4 + j] += acc[ii][j];
#pragma unroll
    for (int j = 0; j < 4; ++j) arow[64 + tx * 4 + j] += acc[ii][4 + j];
  }
}

// ---------------------------------------------------------------------------
// FF2 r8: LDS-FREE flat GEMM (same conversion as ff1_k). A = hpk image
// (64-token half via gaBase; lo at +4096 shorts), B = W2 image.
//  emode 0 (bu):      accum = lv + v            (store, levels 1..5)
//  emode 1 (td):      l==0: accum=lv+tokens+v;  else accum += v
// ---------------------------------------------------------------------------
__global__ __launch_bounds__(256, 4) void mfma_ff2(
    const short* __restrict__ hpk, const short* __restrict__ Wb,
    const float* __restrict__ b2, const float* __restrict__ lv,
    const float* __restrict__ tokens, float* __restrict__ accum,
    int olvbase, int emode)
{
  const int per_x = gridDim.x >> 3;
  const int gid = (blockIdx.x & 7) * per_x + (blockIdx.x >> 3);
  const int nt2 = gid & 3;
  const int tile = gid >> 2;
  const int mt2 = tile & 31;          // 64-token tiles
  const int z = tile >> 5;

  const int tid = threadIdx.x, lane = tid & 63, w = tid >> 6;
  const int wm = (w >> 1) * 32, wn = (w & 1) * 64;
  // (wm>>4)*512 = wm*32 = wm<<5 ; half-select for the 64-token tile is in gaBase
  const short* ga = hpk + (size_t)(z * 16 + (mt2 >> 1)) * 64 * 8192
                    + (size_t)(mt2 & 1) * 2048 + (wm << 5) + lane * 8;
  const short* gb = Wb + (size_t)(z * 4 + nt2) * 64 * 8192
                    + (wn << 5) + lane * 8;

  f32x4 acc[2][4];
#pragma unroll
  for (int i = 0; i < 2; ++i)
#pragma unroll
    for (int j = 0; j < 4; ++j) acc[i][j] = (f32x4)(0.0f);

  for (int kt = 0; kt < 64; ++kt) {
    const short* pa = ga + (size_t)kt * 8192;
    const short* pb = gb + (size_t)kt * 8192;
    bf16x8 ah[2], al[2], bh[4], bl[4];
#pragma unroll
    for (int i = 0; i < 2; ++i) {
      ah[i] = *(const bf16x8*)(pa + i * 512);
      al[i] = *(const bf16x8*)(pa + 4096 + i * 512);
    }
#pragma unroll
    for (int j = 0; j < 4; ++j) {
      bh[j] = *(const bf16x8*)(pb + j * 512);
      bl[j] = *(const bf16x8*)(pb + 4096 + j * 512);
    }
#pragma unroll
    for (int j = 0; j < 4; ++j)
#pragma unroll
      for (int i = 0; i < 2; ++i)
        acc[i][j] = __builtin_amdgcn_mfma_f32_16x16x32_bf16(
            ah[i], bh[j], acc[i][j], 0, 0, 0);
#pragma unroll
    for (int j = 0; j < 4; ++j)
#pragma unroll
      for (int i = 0; i < 2; ++i)
        acc[i][j] = __builtin_amdgcn_mfma_f32_16x16x32_bf16(
            al[i], bh[j], acc[i][j], 0, 0, 0);
#pragma unroll
    for (int j = 0; j < 4; ++j)
#pragma unroll
      for (int i = 0; i < 2; ++i)
        acc[i][j] = __builtin_amdgcn_mfma_f32_16x16x32_bf16(
            ah[i], bl[j], acc[i][j], 0, 0, 0);
  }

  const int q = lane >> 4, t = lane & 15;
  const float* b2g = b2 + (size_t)z * 512;
  const int level = olvbase + z;
#pragma unroll
  for (int i = 0; i < 2; ++i) {
#pragma unroll
    for (int r = 0; r < 4; ++r) {
      int m = mt2 * 64 + wm + i * 16 + q * 4 + r;
      int b = m >> 8, n = m & 255;
      size_t rowoff = ((size_t)(b * L6 + level) * 256 + n) * 512;
      float* arow = accum + rowoff;
      const float* lrow = lv + rowoff;
      const float* trow = tokens + (size_t)m * 512;
#pragma unroll
      for (int j = 0; j < 4; ++j) {
        int col = nt2 * 128 + wn + j * 16 + t;
        float v = acc[i][j][r] + b2g[col];
        if (emode == 0)                       arow[col] = lrow[col] + v;
        else if (level == 0)                  arow[col] = lrow[col] + trow[col] + v;
        else                                  arow[col] += v;
      }
    }
  }
}

// ---------------------------------------------------------------------------
// combine3: lv = accum/contrib, write dout on last iter, fused next-iter
// A-packing, and fused exact-fp32 row-norm via 64-lane butterfly.
// ---------------------------------------------------------------------------
__global__ __launch_bounds__(256) void combine3(
    const float* __restrict__ accum, const float* __restrict__ pos,
    float* __restrict__ lv_out, short* __restrict__ Abu,
    short* __restrict__ Atd, float* __restrict__ invn,
    float* __restrict__ dout, int last)
{
  int t = blockIdx.x * 256 + threadIdx.x;   // 786,432 total
  int d8 = t & 63;
  int n = (t >> 6) & 255;
  int v = t >> 14;                          // b*6 + l, 0..47
  int l = v % 6, b = v / 6;
  int bn = (b << 8) | n;
  size_t idx = ((size_t)v * 256 + n) * 512 + d8 * 8;
  float4 a0 = *(const float4*)(accum + idx);
  float4 a1 = *(const float4*)(accum + idx + 4);
  float sc = (l == 5) ? (1.0f / 3.0f) : 0.25f;
  float r[8];
  r[0] = a0.x * sc; r[1] = a0.y * sc; r[2] = a0.z * sc; r[3] = a0.w * sc;
  r[4] = a1.x * sc; r[5] = a1.y * sc; r[6] = a1.z * sc; r[7] = a1.w * sc;
  *(float4*)(lv_out + idx) = make_float4(r[0], r[1], r[2], r[3]);
  *(float4*)(lv_out + idx + 4) = make_float4(r[4], r[5], r[6], r[7]);
  if (last) {
    float* dp = dout + ((size_t)bn * 6 + l) * 512 + d8 * 8;
    *(float4*)dp = make_float4(r[0], r[1], r[2], r[3]);
    *(float4*)(dp + 4) = make_float4(r[4], r[5], r[6], r[7]);
  }
  // fused row norm: wave == one (v,n) row (d8 = lane)
  {
    float s8 = 0.f;
#pragma unroll
    for (int j = 0; j < 8; ++j) s8 = fmaf(r[j], r[j], s8);
#pragma unroll
    for (int o = 1; o < 64; o <<= 1) s8 += __shfl_xor(s8, o);
    if (d8 == 0) invn[(size_t)v * 256 + n] = 1.0f / fmaxf(sqrtf(s8), 1e-12f);
  }
  int m = bn;
  int mt = m >> 7;
  int kt = d8 >> 2;
  int s = (((m & 127) >> 4) << 6) | (((d8 & 3) << 4) | (m & 15));
  unsigned short hi[8], lo[8];
  if (l < 5) {
    size_t blk = ((size_t)(l * 16 + mt) * 16 + kt) * 8192;
#pragma unroll
    for (int j = 0; j < 8; ++j) split2(r[j], &hi[j], &lo[j]);
    *(int4*)(Abu + blk + s * 8) = pack8(hi);
    *(int4*)(Abu + blk + 4096 + s * 8) = pack8(lo);
  }
  if (l >= 1) {
    const float* pp = pos + (size_t)n * 512 + d8 * 8;
    float4 p0 = *(const float4*)pp;
    float4 p1 = *(const float4*)(pp + 4);
    float y[8] = {r[0] + p0.x, r[1] + p0.y, r[2] + p0.z, r[3] + p0.w,
                  r[4] + p1.x, r[5] + p1.y, r[6] + p1.z, r[7] + p1.w};
    size_t blk = ((size_t)((l - 1) * 16 + mt) * 16 + kt) * 8192;
#pragma unroll
    for (int j = 0; j < 8; ++j) split2(y[j], &hi[j], &lo[j]);
    *(int4*)(Atd + blk + s * 8) = pack8(hi);
    *(int4*)(Atd + blk + 4096 + s * 8) = pack8(lo);
  }
}

// ---------------------------------------------------------------------------
extern "C" void kernel_launch(void* const* d_in, const int* in_sizes, int n_in,
                              void* d_out, int out_size, void* d_ws, size_t ws_size,
                              hipStream_t stream)
{
  const float* img   = (const float*)d_in[0];
  const float* Wp    = (const float*)d_in[1];
  const float* bp    = (const float*)d_in[2];
  const float* pos   = (const float*)d_in[3];
  const float* initl = (const float*)d_in[4];
  const float* buW1  = (const float*)d_in[5];
  const float* bub1  = (const float*)d_in[6];
  const float* buW2  = (const float*)d_in[7];
  const float* bub2  = (const float*)d_in[8];
  const float* tdW1  = (const float*)d_in[9];
  const float* tdb1  = (const float*)d_in[10];
  const float* tdW2  = (const float*)d_in[11];
  const float* tdb2  = (const float*)d_in[12];

  float* ws = (float*)d_ws;
  const size_t LV = (size_t)8 * 6 * 256 * 512;   // 6,291,456 floats
  float* lv     = ws;
  float* tokens = lv + LV;                        // 1,048,576
  float* accum  = tokens + 1048576ull;            // 6,291,456
  short* W1all  = (short*)(accum + LV);           // 20,971,520 shorts
  short* W2all  = W1all + 20971520ull;            // 20,971,520 shorts
  short* Apk    = W2all + 20971520ull;            // 20,971,520 shorts
  short* hall   = Apk + 20971520ull;              // 41,943,040 shorts (5z hi/lo)
  float* invn   = (float*)(hall + 41943040ull);   // 48*256 f32 = 49,152 B
  // total = 264,241,152 + 49,152 = 264,290,304 B == proven capacity

  // attnb aliases hall's upper half (12.6 MB needed, 42 MB available);
  // it lives only between attn_k and cons_k, and hall is rewritten by the
  // NEXT iteration's ff1 passes after cons_k has consumed it.
  float* attnb = (float*)(hall + 20971520ull);
  float* dout  = (float*)d_out;

  pack_w<<<2560, 256, 0, stream>>>(buW1, W1all, 16, 16);
  pack_w<<<2560, 256, 0, stream>>>(tdW1, W1all + 5 * SH_W_GRP, 16, 16);
  pack_w<<<2560, 256, 0, stream>>>(buW2, W2all, 64, 4);
  pack_w<<<2560, 256, 0, stream>>>(tdW2, W2all + 5 * SH_W_GRP, 64, 4);

  patch_embed<<<2048, 256, 0, stream>>>(img, Wp, bp, tokens);
  init_lv_kernel<<<6144, 256, 0, stream>>>(initl, lv);
  norm0_k<<<48, 256, 0, stream>>>(lv, invn);
  pack_A<<<1280, 256, 0, stream>>>(lv, pos, Apk, Apk + SH_A_TDOFF);

  for (int it = 0; it < 12; ++it) {
    // K1: ff1-bu (fills hall)
    ff1_k<<<1280, 256, 0, stream>>>(W1all, Apk, bub1, hall);
    // K2: ff2-bu emode0 (store accum = lv + v, levels 1..5)
    mfma_ff2<<<640, 256, 0, stream>>>(hall, W2all, bub2, lv, tokens, accum, 1, 0);
    // K3: ff1-td (refills hall)
    ff1_k<<<1280, 256, 0, stream>>>(W1all + 5 * SH_W_GRP, Apk + SH_A_TDOFF,
                                    tdb1, hall);
    // K4: ff2-td emode1 (level0 store lv+tokens+v; levels 1..4 RMW)
    mfma_ff2<<<640, 256, 0, stream>>>(hall, W2all + 5 * SH_W_GRP, tdb2, lv,
                                      tokens, accum, 0, 1);
    // K5: MFMA attention (reads Apk bu-image + invn; lv only for level 5)
    attn_k<<<384, 256, 0, stream>>>(lv, Apk, invn, attnb);
    // K6: consensus RMW into accum
    cons_k<<<768, 256, 0, stream>>>(attnb, lv, accum);
    // K7: combine + dout + next-iter A-pack + fused norms
    combine3<<<3072, 256, 0, stream>>>(accum, pos, lv, Apk, Apk + SH_A_TDOFF,
                                       invn, dout, it == 11 ? 1 : 0);
  }
}

// Round 9
// 4711.452 us; speedup vs baseline: 1.1301x; 1.1301x over previous
//
#include <hip/hip_runtime.h>
#include <math.h>

// Problem constants: B=8, S=224, P=14, D=512, L=6, NPS=16, N=256, G=5, H=2048, iters=12
#define L6 6

typedef __attribute__((ext_vector_type(8))) short bf16x8;   // 8 bf16 in 4 VGPRs
typedef __attribute__((ext_vector_type(4))) float f32x4;    // MFMA accum

#define SH_W_GRP   2097152ull   // 512*2048 hi/lo bf16 (both W1 and W2)
#define SH_A_GRP   2097152ull   // 2048 tok * 512 d hi/lo
#define SH_A_TDOFF 10485760ull  // Atd offset inside Apk (5 groups)

// Exact gelu (erff): r10-proven epilogue.
__device__ __forceinline__ float gelu_exact(float x) {
  return 0.5f * x * (1.0f + erff(x * 0.70710678118654752f));
}

__device__ __forceinline__ unsigned short bf16_rn(float x) {
  unsigned u = __float_as_uint(x);
  unsigned r = u + 0x7FFFu + ((u >> 16) & 1u);
  return (unsigned short)(r >> 16);
}
__device__ __forceinline__ float bf16_f(unsigned short h) {
  return __uint_as_float(((unsigned)h) << 16);
}
__device__ __forceinline__ void split2(float x, unsigned short* h, unsigned short* l) {
  unsigned short hh = bf16_rn(x);
  *h = hh;
  *l = bf16_rn(x - bf16_f(hh));
}
__device__ __forceinline__ int4 pack8(const unsigned short* v) {
  return make_int4((int)((unsigned)v[0] | ((unsigned)v[1] << 16)),
                   (int)((unsigned)v[2] | ((unsigned)v[3] << 16)),
                   (int)((unsigned)v[4] | ((unsigned)v[5] << 16)),
                   (int)((unsigned)v[6] | ((unsigned)v[7] << 16)));
}

__device__ __forceinline__ void gload16(const void* g, void* l) {
  __builtin_amdgcn_global_load_lds(
      (const __attribute__((address_space(1))) void*)g,
      (__attribute__((address_space(3))) void*)l, 16, 0, 0);
}

// ---------------------------------------------------------------------------
// Patch embedding
// ---------------------------------------------------------------------------
__global__ __launch_bounds__(256) void patch_embed(
    const float* __restrict__ img, const float* __restrict__ Wp,
    const float* __restrict__ bp, float* __restrict__ tokens)
{
  __shared__ float xs[588];
  const int bn = blockIdx.x;
  const int b = bn >> 8, n = bn & 255;
  const int i = n >> 4, j = n & 15;
  for (int k = threadIdx.x; k < 588; k += 256) {
    int c = k % 3;
    int t = k / 3;
    int pc = t % 14;
    int pr = t / 14;
    xs[k] = img[(((size_t)(b * 3 + c) * 224) + (i * 14 + pr)) * 224 + (j * 14 + pc)];
  }
  __syncthreads();
  const int d0 = threadIdx.x, d1 = threadIdx.x + 256;
  float a0 = 0.f, a1 = 0.f;
  for (int k = 0; k < 588; ++k) {
    float x = xs[k];
    a0 = fmaf(x, Wp[(size_t)k * 512 + d0], a0);
    a1 = fmaf(x, Wp[(size_t)k * 512 + d1], a1);
  }
  tokens[(size_t)bn * 512 + d0] = a0 + bp[d0];
  tokens[(size_t)bn * 512 + d1] = a1 + bp[d1];
}

// ---------------------------------------------------------------------------
__global__ __launch_bounds__(256) void init_lv_kernel(
    const float* __restrict__ initl, float* __restrict__ lv)
{
  int f = blockIdx.x * 256 + threadIdx.x;
  int d4 = f & 127;
  int l = (f >> 15) % 6;
  float4 v = *(const float4*)(initl + (size_t)l * 512 + d4 * 4);
  *(float4*)(lv + (size_t)f * 4) = v;
}

// ---------------------------------------------------------------------------
// Startup norms: invn[bl][n] = 1/max(||lv[bl,n,:]||, 1e-12). One-shot;
// steady-state values produced by combine3's fused wave-reduce.
// ---------------------------------------------------------------------------
__global__ __launch_bounds__(256) void norm0_k(
    const float* __restrict__ lv, float* __restrict__ invn)
{
  int bl = blockIdx.x;
  int n = threadIdx.x;
  const float* row = lv + ((size_t)bl * 256 + n) * 512;
  float ss = 0.f;
  for (int k = 0; k < 512; k += 4) {
    float4 v = *(const float4*)(row + k);
    ss = fmaf(v.x, v.x, ss);
    ss = fmaf(v.y, v.y, ss);
    ss = fmaf(v.z, v.z, ss);
    ss = fmaf(v.w, v.w, ss);
  }
  invn[(size_t)bl * 256 + n] = 1.0f / fmaxf(sqrtf(ss), 1e-12f);
}

// ---------------------------------------------------------------------------
// Pack weights fp32 [G][K][N] -> hi/lo bf16 fragment-image.
// ---------------------------------------------------------------------------
__global__ __launch_bounds__(256) void pack_w(
    const float* __restrict__ src, short* __restrict__ dst, int KT, int NT)
{
  int sidx = blockIdx.x * 256 + threadIdx.x;
  int slot = sidx & 511;
  int blk = sidx >> 9;
  int kt = blk % KT;
  int rest = blk / KT;
  int nt = rest % NT;
  int g = rest / NT;
  int f = slot >> 6, lane = slot & 63;
  int N = NT * 128, K = KT * 32;
  int n = nt * 128 + f * 16 + (lane & 15);
  int k0 = kt * 32 + (lane >> 4) * 8;
  const float* s = src + ((size_t)g * K + k0) * N + n;
  unsigned short hi[8], lo[8];
#pragma unroll
  for (int j = 0; j < 8; ++j) split2(s[(size_t)j * N], &hi[j], &lo[j]);
  short* d = dst + (size_t)blk * 8192 + slot * 8;
  *(int4*)d = pack8(hi);
  *(int4*)(d + 4096) = pack8(lo);
}

// ---------------------------------------------------------------------------
// Startup A-pack (steady-state fused into combine3).
// ---------------------------------------------------------------------------
__global__ __launch_bounds__(256) void pack_A(
    const float* __restrict__ lv, const float* __restrict__ pos,
    short* __restrict__ Abu, short* __restrict__ Atd)
{
  const int bx = blockIdx.x;              // 0..1279
  const int lg = bx >> 8, mt = (bx >> 4) & 15, kt = bx & 15;
  const size_t blk = (size_t)bx * 8192;
#pragma unroll
  for (int ss = 0; ss < 2; ++ss) {
    int s = threadIdx.x + ss * 256;
    int f = s >> 6, l = s & 63;
    int m = mt * 128 + (f << 4) + (l & 15);
    int b = m >> 8, n = m & 255;
    int d = kt * 32 + ((l >> 4) << 3);
    const float* pbu = lv + ((size_t)(b * L6 + lg) * 256 + n) * 512 + d;
    const float* ptd = lv + ((size_t)(b * L6 + lg + 1) * 256 + n) * 512 + d;
    const float* pp = pos + (size_t)n * 512 + d;
    float4 u0 = *(const float4*)pbu;
    float4 u1 = *(const float4*)(pbu + 4);
    float xv[8] = {u0.x, u0.y, u0.z, u0.w, u1.x, u1.y, u1.z, u1.w};
    unsigned short hi[8], lo[8];
#pragma unroll
    for (int j = 0; j < 8; ++j) split2(xv[j], &hi[j], &lo[j]);
    *(int4*)(Abu + blk + s * 8) = pack8(hi);
    *(int4*)(Abu + blk + 4096 + s * 8) = pack8(lo);
    float4 v0 = *(const float4*)ptd;
    float4 v1 = *(const float4*)(ptd + 4);
    float4 p0 = *(const float4*)pp;
    float4 p1 = *(const float4*)(pp + 4);
    float yv[8] = {v0.x + p0.x, v0.y + p0.y, v0.z + p0.z, v0.w + p0.w,
                   v1.x + p1.x, v1.y + p1.y, v1.z + p1.z, v1.w + p1.w};
#pragma unroll
    for (int j = 0; j < 8; ++j) split2(yv[j], &hi[j], &lo[j]);
    *(int4*)(Atd + blk + s * 8) = pack8(hi);
    *(int4*)(Atd + blk + 4096 + s * 8) = pack8(lo);
  }
}

// ---------------------------------------------------------------------------
// FF1 r8-proven: LDS-FREE flat GEMM (~56us, was 109 LDS-staged). Operands in
// fragment-image order -> global_load_dwordx4 straight to VGPR, no barriers;
// TLP hides latency. A/B panels L2-resident (256KB/tile, 16-block reuse).
// Bit-identical to LDS version. (ff2 flat REGRESSED 60->130: its A-stream
// (40MB hpk) thrashes the 4MB/XCD L2 and evicts the shared B panel — keep
// ff2 LDS-staged. FETCH evidence: 95MB/dispatch vs 60MB unique.)
// ---------------------------------------------------------------------------
__global__ __launch_bounds__(256, 3) void ff1_k(
    const short* __restrict__ Wa, const short* __restrict__ Ap,
    const float* __restrict__ b1, short* __restrict__ hpk)
{
  const int per_x = gridDim.x >> 3;
  const int gid = (blockIdx.x & 7) * per_x + (blockIdx.x >> 3);
  const int tt = gid & 15;
  const int tile = gid >> 4;
  const int ht = tile & 15;
  const int z = tile >> 4;
  const int tid = threadIdx.x, lane = tid & 63, w = tid >> 6;
  const int wm = (w >> 1) * 64, wn = (w & 1) * 64;
  // (wm>>4)*512 = wm*32 = wm<<5 : this wave's fragment base in the image
  const short* ga = Wa + (size_t)(z * 16 + ht) * 16 * 8192 + (wm << 5) + lane * 8;
  const short* gb = Ap + (size_t)(z * 16 + tt) * 16 * 8192 + (wn << 5) + lane * 8;

  f32x4 acc[4][4];
#pragma unroll
  for (int i = 0; i < 4; ++i)
#pragma unroll
    for (int j = 0; j < 4; ++j) acc[i][j] = (f32x4)(0.0f);

  for (int kt = 0; kt < 16; ++kt) {
    const short* pa = ga + (size_t)kt * 8192;
    const short* pb = gb + (size_t)kt * 8192;
    bf16x8 ah[4], al[4], bh[4], bl[4];
#pragma unroll
    for (int i = 0; i < 4; ++i) {
      ah[i] = *(const bf16x8*)(pa + i * 512);
      al[i] = *(const bf16x8*)(pa + 4096 + i * 512);
    }
#pragma unroll
    for (int j = 0; j < 4; ++j) {
      bh[j] = *(const bf16x8*)(pb + j * 512);
      bl[j] = *(const bf16x8*)(pb + 4096 + j * 512);
    }
    // pass 1: A_hi * B_hi
#pragma unroll
    for (int j = 0; j < 4; ++j)
#pragma unroll
      for (int i = 0; i < 4; ++i)
        acc[i][j] = __builtin_amdgcn_mfma_f32_16x16x32_bf16(
            ah[i], bh[j], acc[i][j], 0, 0, 0);
    // pass 2: A_lo * B_hi
#pragma unroll
    for (int j = 0; j < 4; ++j)
#pragma unroll
      for (int i = 0; i < 4; ++i)
        acc[i][j] = __builtin_amdgcn_mfma_f32_16x16x32_bf16(
            al[i], bh[j], acc[i][j], 0, 0, 0);
    // pass 3: A_hi * B_lo
#pragma unroll
    for (int j = 0; j < 4; ++j)
#pragma unroll
      for (int i = 0; i < 4; ++i)
        acc[i][j] = __builtin_amdgcn_mfma_f32_16x16x32_bf16(
            ah[i], bl[j], acc[i][j], 0, 0, 0);
  }

  const int q = lane >> 4, t = lane & 15;
  const float* b1g = b1 + (size_t)z * 2048;
#pragma unroll
  for (int i = 0; i < 4; ++i) {
    int Hb = ht * 128 + wm + i * 16 + q * 4;
    float4 bv = *(const float4*)(b1g + Hb);
    float bb[4] = {bv.x, bv.y, bv.z, bv.w};
    int kt2 = Hb >> 5;
    int g2 = (Hb >> 3) & 3;
    int jb = Hb & 7;                       // 0 or 4
    size_t blkbase = ((size_t)(z * 16 + tt) * 64 + kt2) * 8192;
#pragma unroll
    for (int j = 0; j < 4; ++j) {
      int f2 = (wn >> 4) + j;
      size_t off = blkbase + (size_t)(f2 * 64 + g2 * 16 + t) * 8 + jb;
      unsigned short hi[4], lo[4];
#pragma unroll
      for (int r = 0; r < 4; ++r) {
        float x = gelu_exact(acc[i][j][r] + bb[r]);
        split2(x, &hi[r], &lo[r]);
      }
      *(uint2*)(hpk + off) =
          make_uint2((unsigned)hi[0] | ((unsigned)hi[1] << 16),
                     (unsigned)hi[2] | ((unsigned)hi[3] << 16));
      *(uint2*)(hpk + off + 4096) =
          make_uint2((unsigned)lo[0] | ((unsigned)lo[1] << 16),
                     (unsigned)lo[2] | ((unsigned)lo[3] << 16));
    }
  }
}

// ---------------------------------------------------------------------------
// Attention r7: MFMA Gram with norm table (4731us-best configuration).
// ---------------------------------------------------------------------------
__global__ __launch_bounds__(256, 3) void attn_k(
    const float* __restrict__ lv, const short* __restrict__ Apk,
    const float* __restrict__ invn, float* __restrict__ attnb)
{
  __shared__ __align__(16) short Bhi[8192];   // 16 frags x 64 lanes x 8
  __shared__ __align__(16) short Blo[8192];
  __shared__ float scL[256];
  __shared__ float red[32][4];
  const int a = blockIdx.x;
  const int s = a >> 3;
  const int b = a & 7;                 // batch == XCD group
  const int l = s >> 3;                // level 0..5
  const int bl = b * 6 + l;
  const int i0 = (s & 7) * 32;
  const float* base = lv + (size_t)bl * 131072;
  const int tid = threadIdx.x, lane = tid & 63, w = tid >> 6;
  const int q = lane >> 4, c = lane & 15;

  scL[tid] = invn[(size_t)bl * 256 + tid];   // one row scale per thread

  f32x4 acc[2][4];
#pragma unroll
  for (int i = 0; i < 2; ++i)
#pragma unroll
    for (int j = 0; j < 4; ++j) acc[i][j] = (f32x4)(0.0f);

  // Apk bu-image sub-blocks for this (b,l): tokens n 0..127 -> tile 2b,
  // n 128..255 -> tile 2b+1. Valid only for l<5.
  const short* src0 = Apk + ((size_t)(l * 16 + 2 * b) * 16) * 8192;
  const short* src1 = Apk + ((size_t)(l * 16 + 2 * b + 1) * 16) * 8192;

  for (int kt = 0; kt < 16; ++kt) {
    __syncthreads();                    // prev step's LDS reads done
    if (l < 5) {
      const char* p0 = (const char*)(src0 + (size_t)kt * 8192);
      const char* p1 = (const char*)(src1 + (size_t)kt * 8192);
      gload16(p0 + tid * 16,         (char*)Bhi + tid * 16);
      gload16(p0 + 4096 + tid * 16,  (char*)Bhi + 4096 + tid * 16);
      gload16(p0 + 8192 + tid * 16,  (char*)Blo + tid * 16);
      gload16(p0 + 12288 + tid * 16, (char*)Blo + 4096 + tid * 16);
      gload16(p1 + tid * 16,         (char*)Bhi + 8192 + tid * 16);
      gload16(p1 + 4096 + tid * 16,  (char*)Bhi + 12288 + tid * 16);
      gload16(p1 + 8192 + tid * 16,  (char*)Blo + 8192 + tid * 16);
      gload16(p1 + 12288 + tid * 16, (char*)Blo + 12288 + tid * 16);
    } else {
      const int k0 = kt * 32;
#pragma unroll
      for (int it = 0; it < 8; ++it) {
        int f = it * 256 + tid;
        int j = f >> 3, c4 = f & 7;
        float4 v = *(const float4*)(base + (size_t)j * 512 + k0 + c4 * 4);
        unsigned short hi[4], lo[4];
        split2(v.x, &hi[0], &lo[0]);
        split2(v.y, &hi[1], &lo[1]);
        split2(v.z, &hi[2], &lo[2]);
        split2(v.w, &hi[3], &lo[3]);
        int fg = j >> 4;
        int la = (c4 >> 1) * 16 + (j & 15);
        int half = (c4 & 1) * 4;
        *(uint2*)&Bhi[fg * 512 + la * 8 + half] =
            make_uint2((unsigned)hi[0] | ((unsigned)hi[1] << 16),
                       (unsigned)hi[2] | ((unsigned)hi[3] << 16));
        *(uint2*)&Blo[fg * 512 + la * 8 + half] =
            make_uint2((unsigned)lo[0] | ((unsigned)lo[1] << 16),
                       (unsigned)lo[2] | ((unsigned)lo[3] << 16));
      }
    }
    __syncthreads();                    // staging complete
    bf16x8 ah[2], al[2], bh[4], blv[4];
#pragma unroll
    for (int i = 0; i < 2; ++i) {
      int fg = (i0 >> 4) + i;
      ah[i] = *(const bf16x8*)&Bhi[fg * 512 + lane * 8];
      al[i] = *(const bf16x8*)&Blo[fg * 512 + lane * 8];
    }
#pragma unroll
    for (int j = 0; j < 4; ++j) {
      int fg = w * 4 + j;
      bh[j] = *(const bf16x8*)&Bhi[fg * 512 + lane * 8];
      blv[j] = *(const bf16x8*)&Blo[fg * 512 + lane * 8];
    }
#pragma unroll
    for (int j = 0; j < 4; ++j)
#pragma unroll
      for (int i = 0; i < 2; ++i)
        acc[i][j] = __builtin_amdgcn_mfma_f32_16x16x32_bf16(
            ah[i], bh[j], acc[i][j], 0, 0, 0);
#pragma unroll
    for (int j = 0; j < 4; ++j)
#pragma unroll
      for (int i = 0; i < 2; ++i)
        acc[i][j] = __builtin_amdgcn_mfma_f32_16x16x32_bf16(
            al[i], bh[j], acc[i][j], 0, 0, 0);
#pragma unroll
    for (int j = 0; j < 4; ++j)
#pragma unroll
      for (int i = 0; i < 2; ++i)
        acc[i][j] = __builtin_amdgcn_mfma_f32_16x16x32_bf16(
            ah[i], blv[j], acc[i][j], 0, 0, 0);
  }
  __syncthreads();                      // scL writes visible (also from loop)

  const float rs = 0.04419417382415922f;  // 512^-0.5
  // scale + diag; value at (ai,bj,r): i = i0+ai*16+q*4+r, j = w*64+bj*16+c
#pragma unroll
  for (int ai = 0; ai < 2; ++ai)
#pragma unroll
    for (int bj = 0; bj < 4; ++bj)
#pragma unroll
      for (int r = 0; r < 4; ++r) {
        int i = i0 + ai * 16 + q * 4 + r;
        int j = w * 64 + bj * 16 + c;
        float sv = acc[ai][bj][r] * scL[j] * rs;
        if (j == i) sv = -0.0005f;
        acc[ai][bj][r] = sv;
      }
  // wave-local row max (over this wave's 64 j), then cross-wave via red
  float mx[2][4];
#pragma unroll
  for (int ai = 0; ai < 2; ++ai)
#pragma unroll
    for (int r = 0; r < 4; ++r) {
      float m = fmaxf(fmaxf(acc[ai][0][r], acc[ai][1][r]),
                      fmaxf(acc[ai][2][r], acc[ai][3][r]));
      m = fmaxf(m, __shfl_xor(m, 1));
      m = fmaxf(m, __shfl_xor(m, 2));
      m = fmaxf(m, __shfl_xor(m, 4));
      m = fmaxf(m, __shfl_xor(m, 8));
      mx[ai][r] = m;
    }
  if (c == 0) {
#pragma unroll
    for (int ai = 0; ai < 2; ++ai)
#pragma unroll
      for (int r = 0; r < 4; ++r) red[ai * 16 + q * 4 + r][w] = mx[ai][r];
  }
  __syncthreads();
#pragma unroll
  for (int ai = 0; ai < 2; ++ai)
#pragma unroll
    for (int r = 0; r < 4; ++r) {
      int row = ai * 16 + q * 4 + r;
      mx[ai][r] = fmaxf(fmaxf(red[row][0], red[row][1]),
                        fmaxf(red[row][2], red[row][3]));
    }
  __syncthreads();                      // before red reuse for sums
  float sm[2][4];
#pragma unroll
  for (int ai = 0; ai < 2; ++ai)
#pragma unroll
    for (int r = 0; r < 4; ++r) {
      float t = 0.f;
#pragma unroll
      for (int bj = 0; bj < 4; ++bj) {
        float e = expf(acc[ai][bj][r] - mx[ai][r]);
        acc[ai][bj][r] = e;
        t += e;
      }
      t += __shfl_xor(t, 1);
      t += __shfl_xor(t, 2);
      t += __shfl_xor(t, 4);
      t += __shfl_xor(t, 8);
      sm[ai][r] = t;
    }
  if (c == 0) {
#pragma unroll
    for (int ai = 0; ai < 2; ++ai)
#pragma unroll
      for (int r = 0; r < 4; ++r) red[ai * 16 + q * 4 + r][w] = sm[ai][r];
  }
  __syncthreads();
  float* ob = attnb + (size_t)bl * 65536;
#pragma unroll
  for (int ai = 0; ai < 2; ++ai)
#pragma unroll
    for (int r = 0; r < 4; ++r) {
      int row = ai * 16 + q * 4 + r;
      float S = red[row][0] + red[row][1] + red[row][2] + red[row][3];
      float inv = 1.0f / S;
      int i = i0 + row;
#pragma unroll
      for (int bj = 0; bj < 4; ++bj) {
        int j = w * 64 + bj * 16 + c;
        ob[(size_t)i * 256 + j] = acc[ai][bj][r] * inv;
      }
    }
}

// ---------------------------------------------------------------------------
// Consensus: accum += attnb @ lv (pure RMW). Grid 768, XCD-grouped by bl.
// ---------------------------------------------------------------------------
__global__ __launch_bounds__(256) void cons_k(
    const float* __restrict__ attnb, const float* __restrict__ lv,
    float* __restrict__ accum)
{
  __shared__ __align__(16) char smemraw[25088];
  const int a = blockIdx.x;
  const int s = a >> 3;
  const int bl = (a & 7) * 6 + (s >> 4);
  const int tile = s & 15;
  int it0 = (tile >> 2) * 64;
  int dt0 = (tile & 3) * 128;
  const float* A = attnb + (size_t)bl * 65536;
  const float* Bm = lv + (size_t)bl * 131072;
  float (*Ast)[68] = (float(*)[68])smemraw;
  float (*Bs)[128] = (float(*)[128])(smemraw + 8704);
  const int tid = threadIdx.x;
  const int ty = tid >> 4, tx = tid & 15;
  float acc[4][8];
#pragma unroll
  for (int i = 0; i < 4; ++i)
#pragma unroll
    for (int j = 0; j < 8; ++j) acc[i][j] = 0.f;

  for (int k0 = 0; k0 < 256; k0 += 32) {
#pragma unroll
    for (int it = 0; it < 2; ++it) {
      int f = it * 256 + tid;
      int r = f >> 3, c4 = f & 7;
      float4 v = *(const float4*)(A + (size_t)(it0 + r) * 256 + k0 + c4 * 4);
      Ast[c4 * 4 + 0][r] = v.x;
      Ast[c4 * 4 + 1][r] = v.y;
      Ast[c4 * 4 + 2][r] = v.z;
      Ast[c4 * 4 + 3][r] = v.w;
    }
#pragma unroll
    for (int it = 0; it < 4; ++it) {
      int kr = (tid >> 5) + it * 8;
      int c4 = tid & 31;
      *(float4*)&Bs[kr][c4 * 4] =
          *(const float4*)(Bm + (size_t)(k0 + kr) * 512 + dt0 + c4 * 4);
    }
    __syncthreads();
#pragma unroll 8
    for (int k = 0; k < 32; ++k) {
      float4 av = *(const float4*)&Ast[k][ty * 4];
      float4 b0 = *(const float4*)&Bs[k][tx * 4];
      float4 b1 = *(const float4*)&Bs[k][64 + tx * 4];
      float avv[4] = {av.x, av.y, av.z, av.w};
      float bv[8] = {b0.x, b0.y, b0.z, b0.w, b1.x, b1.y, b1.z, b1.w};
#pragma unroll
      for (int i = 0; i < 4; ++i)
#pragma unroll
        for (int j = 0; j < 8; ++j)
          acc[i][j] = fmaf(avv[i], bv[j], acc[i][j]);
    }
    __syncthreads();
  }
#pragma unroll
  for (int ii = 0; ii < 4; ++ii) {
    int i = it0 + ty * 4 + ii;
    float* arow = accum + (size_t)bl * 131072 + (size_t)i * 512 + dt0;
#pragma unroll
    for (int j = 0; j < 4; ++j) arow[tx * 4 + j] += acc[ii][j];
#pragma unroll
    for (int j = 0; j < 4; ++j) arow[64 + tx * 4 + j] += acc[ii][4 + j];
  }
}

// ---------------------------------------------------------------------------
// FF2: 64(token) x 128(outd) block, 640 blocks, single-buf LDS 24KB.
// r2-proven LDS-staged version (~52-60us). r8's flat conversion REGRESSED
// to 130us: the 40MB hpk A-stream thrashes the 4MB/XCD L2, evicting the
// block-shared W2 B-panel (FETCH 95MB vs 60MB unique). LDS staging reads B
// once per block and keeps it resident — do not flatten this kernel.
//  emode 0 (bu):      accum = lv + v            (store, levels 1..5)
//  emode 1 (td):      l==0: accum=lv+tokens+v;  else accum += v
// ---------------------------------------------------------------------------
__global__ __launch_bounds__(256, 4) void mfma_ff2(
    const short* __restrict__ hpk, const short* __restrict__ Wb,
    const float* __restrict__ b2, const float* __restrict__ lv,
    const float* __restrict__ tokens, float* __restrict__ accum,
    int olvbase, int emode)
{
  const int per_x = gridDim.x >> 3;
  const int gid = (blockIdx.x & 7) * per_x + (blockIdx.x >> 3);
  const int nt2 = gid & 3;
  const int tile = gid >> 2;
  const int mt2 = tile & 31;          // 64-token tiles
  const int z = tile >> 5;

  __shared__ __align__(16) short SA[4096];   // hi 2048 | lo 2048
  __shared__ __align__(16) short SB[8192];   // hi 4096 | lo 4096
  const int tid = threadIdx.x, lane = tid & 63, w = tid >> 6;
  const int wm = (w >> 1) * 32, wn = (w & 1) * 64;
  const short* gaBase = hpk + (size_t)(z * 16 + (mt2 >> 1)) * 64 * 8192
                        + (size_t)(mt2 & 1) * 2048;
  const short* gb = Wb + (size_t)(z * 4 + nt2) * 64 * 8192;

  f32x4 acc[2][4];
#pragma unroll
  for (int i = 0; i < 2; ++i)
#pragma unroll
    for (int j = 0; j < 4; ++j) acc[i][j] = (f32x4)(0.0f);

  for (int kt = 0; kt < 64; ++kt) {
    __syncthreads();
    const char* pa = (const char*)(gaBase + (size_t)kt * 8192);
    const char* pb = (const char*)(gb + (size_t)kt * 8192);
    gload16(pa + w * 1024 + lane * 16, (char*)SA + w * 1024);
    gload16(pa + 8192 + w * 1024 + lane * 16, (char*)SA + 4096 + w * 1024);
#pragma unroll
    for (int c = 0; c < 4; ++c)
      gload16(pb + w * 4096 + c * 1024 + lane * 16,
              (char*)SB + w * 4096 + c * 1024);
    __syncthreads();
    bf16x8 ah[2], al[2];
#pragma unroll
    for (int i = 0; i < 2; ++i) {
      int f = (wm >> 4) + i;
      ah[i] = *(const bf16x8*)&SA[f * 512 + lane * 8];
      al[i] = *(const bf16x8*)&SA[2048 + f * 512 + lane * 8];
    }
#pragma unroll
    for (int jp = 0; jp < 2; ++jp) {
      bf16x8 bh[2], bl[2];
#pragma unroll
      for (int j2 = 0; j2 < 2; ++j2) {
        int f = (wn >> 4) + jp * 2 + j2;
        bh[j2] = *(const bf16x8*)&SB[f * 512 + lane * 8];
        bl[j2] = *(const bf16x8*)&SB[4096 + f * 512 + lane * 8];
      }
#pragma unroll
      for (int j2 = 0; j2 < 2; ++j2)
#pragma unroll
        for (int i = 0; i < 2; ++i)
          acc[i][jp * 2 + j2] = __builtin_amdgcn_mfma_f32_16x16x32_bf16(
              ah[i], bh[j2], acc[i][jp * 2 + j2], 0, 0, 0);
#pragma unroll
      for (int j2 = 0; j2 < 2; ++j2)
#pragma unroll
        for (int i = 0; i < 2; ++i)
          acc[i][jp * 2 + j2] = __builtin_amdgcn_mfma_f32_16x16x32_bf16(
              al[i], bh[j2], acc[i][jp * 2 + j2], 0, 0, 0);
#pragma unroll
      for (int j2 = 0; j2 < 2; ++j2)
#pragma unroll
        for (int i = 0; i < 2; ++i)
          acc[i][jp * 2 + j2] = __builtin_amdgcn_mfma_f32_16x16x32_bf16(
              ah[i], bl[j2], acc[i][jp * 2 + j2], 0, 0, 0);
    }
  }

  const int q = lane >> 4, t = lane & 15;
  const float* b2g = b2 + (size_t)z * 512;
  const int level = olvbase + z;
#pragma unroll
  for (int i = 0; i < 2; ++i) {
#pragma unroll
    for (int r = 0; r < 4; ++r) {
      int m = mt2 * 64 + wm + i * 16 + q * 4 + r;
      int b = m >> 8, n = m & 255;
      size_t rowoff = ((size_t)(b * L6 + level) * 256 + n) * 512;
      float* arow = accum + rowoff;
      const float* lrow = lv + rowoff;
      const float* trow = tokens + (size_t)m * 512;
#pragma unroll
      for (int j = 0; j < 4; ++j) {
        int col = nt2 * 128 + wn + j * 16 + t;
        float v = acc[i][j][r] + b2g[col];
        if (emode == 0)                       arow[col] = lrow[col] + v;
        else if (level == 0)                  arow[col] = lrow[col] + trow[col] + v;
        else                                  arow[col] += v;
      }
    }
  }
}

// ---------------------------------------------------------------------------
// combine3: lv = accum/contrib, write dout on last iter, fused next-iter
// A-packing, and fused exact-fp32 row-norm via 64-lane butterfly.
// ---------------------------------------------------------------------------
__global__ __launch_bounds__(256) void combine3(
    const float* __restrict__ accum, const float* __restrict__ pos,
    float* __restrict__ lv_out, short* __restrict__ Abu,
    short* __restrict__ Atd, float* __restrict__ invn,
    float* __restrict__ dout, int last)
{
  int t = blockIdx.x * 256 + threadIdx.x;   // 786,432 total
  int d8 = t & 63;
  int n = (t >> 6) & 255;
  int v = t >> 14;                          // b*6 + l, 0..47
  int l = v % 6, b = v / 6;
  int bn = (b << 8) | n;
  size_t idx = ((size_t)v * 256 + n) * 512 + d8 * 8;
  float4 a0 = *(const float4*)(accum + idx);
  float4 a1 = *(const float4*)(accum + idx + 4);
  float sc = (l == 5) ? (1.0f / 3.0f) : 0.25f;
  float r[8];
  r[0] = a0.x * sc; r[1] = a0.y * sc; r[2] = a0.z * sc; r[3] = a0.w * sc;
  r[4] = a1.x * sc; r[5] = a1.y * sc; r[6] = a1.z * sc; r[7] = a1.w * sc;
  *(float4*)(lv_out + idx) = make_float4(r[0], r[1], r[2], r[3]);
  *(float4*)(lv_out + idx + 4) = make_float4(r[4], r[5], r[6], r[7]);
  if (last) {
    float* dp = dout + ((size_t)bn * 6 + l) * 512 + d8 * 8;
    *(float4*)dp = make_float4(r[0], r[1], r[2], r[3]);
    *(float4*)(dp + 4) = make_float4(r[4], r[5], r[6], r[7]);
  }
  // fused row norm: wave == one (v,n) row (d8 = lane)
  {
    float s8 = 0.f;
#pragma unroll
    for (int j = 0; j < 8; ++j) s8 = fmaf(r[j], r[j], s8);
#pragma unroll
    for (int o = 1; o < 64; o <<= 1) s8 += __shfl_xor(s8, o);
    if (d8 == 0) invn[(size_t)v * 256 + n] = 1.0f / fmaxf(sqrtf(s8), 1e-12f);
  }
  int m = bn;
  int mt = m >> 7;
  int kt = d8 >> 2;
  int s = (((m & 127) >> 4) << 6) | (((d8 & 3) << 4) | (m & 15));
  unsigned short hi[8], lo[8];
  if (l < 5) {
    size_t blk = ((size_t)(l * 16 + mt) * 16 + kt) * 8192;
#pragma unroll
    for (int j = 0; j < 8; ++j) split2(r[j], &hi[j], &lo[j]);
    *(int4*)(Abu + blk + s * 8) = pack8(hi);
    *(int4*)(Abu + blk + 4096 + s * 8) = pack8(lo);
  }
  if (l >= 1) {
    const float* pp = pos + (size_t)n * 512 + d8 * 8;
    float4 p0 = *(const float4*)pp;
    float4 p1 = *(const float4*)(pp + 4);
    float y[8] = {r[0] + p0.x, r[1] + p0.y, r[2] + p0.z, r[3] + p0.w,
                  r[4] + p1.x, r[5] + p1.y, r[6] + p1.z, r[7] + p1.w};
    size_t blk = ((size_t)((l - 1) * 16 + mt) * 16 + kt) * 8192;
#pragma unroll
    for (int j = 0; j < 8; ++j) split2(y[j], &hi[j], &lo[j]);
    *(int4*)(Atd + blk + s * 8) = pack8(hi);
    *(int4*)(Atd + blk + 4096 + s * 8) = pack8(lo);
  }
}

// ---------------------------------------------------------------------------
extern "C" void kernel_launch(void* const* d_in, const int* in_sizes, int n_in,
                              void* d_out, int out_size, void* d_ws, size_t ws_size,
                              hipStream_t stream)
{
  const float* img   = (const float*)d_in[0];
  const float* Wp    = (const float*)d_in[1];
  const float* bp    = (const float*)d_in[2];
  const float* pos   = (const float*)d_in[3];
  const float* initl = (const float*)d_in[4];
  const float* buW1  = (const float*)d_in[5];
  const float* bub1  = (const float*)d_in[6];
  const float* buW2  = (const float*)d_in[7];
  const float* bub2  = (const float*)d_in[8];
  const float* tdW1  = (const float*)d_in[9];
  const float* tdb1  = (const float*)d_in[10];
  const float* tdW2  = (const float*)d_in[11];
  const float* tdb2  = (const float*)d_in[12];

  float* ws = (float*)d_ws;
  const size_t LV = (size_t)8 * 6 * 256 * 512;   // 6,291,456 floats
  float* lv     = ws;
  float* tokens = lv + LV;                        // 1,048,576
  float* accum  = tokens + 1048576ull;            // 6,291,456
  short* W1all  = (short*)(accum + LV);           // 20,971,520 shorts
  short* W2all  = W1all + 20971520ull;            // 20,971,520 shorts
  short* Apk    = W2all + 20971520ull;            // 20,971,520 shorts
  short* hall   = Apk + 20971520ull;              // 41,943,040 shorts (5z hi/lo)
  float* invn   = (float*)(hall + 41943040ull);   // 48*256 f32 = 49,152 B
  // total = 264,241,152 + 49,152 = 264,290,304 B == proven capacity

  // attnb aliases hall's upper half (12.6 MB needed, 42 MB available);
  // it lives only between attn_k and cons_k, and hall is rewritten by the
  // NEXT iteration's ff1 passes after cons_k has consumed it.
  float* attnb = (float*)(hall + 20971520ull);
  float* dout  = (float*)d_out;

  pack_w<<<2560, 256, 0, stream>>>(buW1, W1all, 16, 16);
  pack_w<<<2560, 256, 0, stream>>>(tdW1, W1all + 5 * SH_W_GRP, 16, 16);
  pack_w<<<2560, 256, 0, stream>>>(buW2, W2all, 64, 4);
  pack_w<<<2560, 256, 0, stream>>>(tdW2, W2all + 5 * SH_W_GRP, 64, 4);

  patch_embed<<<2048, 256, 0, stream>>>(img, Wp, bp, tokens);
  init_lv_kernel<<<6144, 256, 0, stream>>>(initl, lv);
  norm0_k<<<48, 256, 0, stream>>>(lv, invn);
  pack_A<<<1280, 256, 0, stream>>>(lv, pos, Apk, Apk + SH_A_TDOFF);

  for (int it = 0; it < 12; ++it) {
    // K1: ff1-bu (fills hall)
    ff1_k<<<1280, 256, 0, stream>>>(W1all, Apk, bub1, hall);
    // K2: ff2-bu emode0 (store accum = lv + v, levels 1..5)
    mfma_ff2<<<640, 256, 0, stream>>>(hall, W2all, bub2, lv, tokens, accum, 1, 0);
    // K3: ff1-td (refills hall)
    ff1_k<<<1280, 256, 0, stream>>>(W1all + 5 * SH_W_GRP, Apk + SH_A_TDOFF,
                                    tdb1, hall);
    // K4: ff2-td emode1 (level0 store lv+tokens+v; levels 1..4 RMW)
    mfma_ff2<<<640, 256, 0, stream>>>(hall, W2all + 5 * SH_W_GRP, tdb2, lv,
                                      tokens, accum, 0, 1);
    // K5: MFMA attention (reads Apk bu-image + invn; lv only for level 5)
    attn_k<<<384, 256, 0, stream>>>(lv, Apk, invn, attnb);
    // K6: consensus RMW into accum
    cons_k<<<768, 256, 0, stream>>>(attnb, lv, accum);
    // K7: combine + dout + next-iter A-pack + fused norms
    combine3<<<3072, 256, 0, stream>>>(accum, pos, lv, Apk, Apk + SH_A_TDOFF,
                                       invn, dout, it == 11 ? 1 : 0);
  }
}

// Round 10
// 4702.002 us; speedup vs baseline: 1.1324x; 1.0020x over previous
//
#include <hip/hip_runtime.h>
#include <math.h>

// Problem constants: B=8, S=224, P=14, D=512, L=6, NPS=16, N=256, G=5, H=2048, iters=12
#define L6 6

typedef __attribute__((ext_vector_type(8))) short bf16x8;   // 8 bf16 in 4 VGPRs
typedef __attribute__((ext_vector_type(4))) float f32x4;    // MFMA accum

#define SH_W_GRP   2097152ull   // 512*2048 hi/lo bf16 (both W1 and W2)
#define SH_A_GRP   2097152ull   // 2048 tok * 512 d hi/lo
#define SH_A_TDOFF 10485760ull  // Atd offset inside Apk (5 groups)

// Exact gelu (erff): r10-proven epilogue.
__device__ __forceinline__ float gelu_exact(float x) {
  return 0.5f * x * (1.0f + erff(x * 0.70710678118654752f));
}

__device__ __forceinline__ unsigned short bf16_rn(float x) {
  unsigned u = __float_as_uint(x);
  unsigned r = u + 0x7FFFu + ((u >> 16) & 1u);
  return (unsigned short)(r >> 16);
}
__device__ __forceinline__ float bf16_f(unsigned short h) {
  return __uint_as_float(((unsigned)h) << 16);
}
__device__ __forceinline__ void split2(float x, unsigned short* h, unsigned short* l) {
  unsigned short hh = bf16_rn(x);
  *h = hh;
  *l = bf16_rn(x - bf16_f(hh));
}
__device__ __forceinline__ int4 pack8(const unsigned short* v) {
  return make_int4((int)((unsigned)v[0] | ((unsigned)v[1] << 16)),
                   (int)((unsigned)v[2] | ((unsigned)v[3] << 16)),
                   (int)((unsigned)v[4] | ((unsigned)v[5] << 16)),
                   (int)((unsigned)v[6] | ((unsigned)v[7] << 16)));
}

__device__ __forceinline__ void gload16(const void* g, void* l) {
  __builtin_amdgcn_global_load_lds(
      (const __attribute__((address_space(1))) void*)g,
      (__attribute__((address_space(3))) void*)l, 16, 0, 0);
}

// ---------------------------------------------------------------------------
// Patch embedding
// ---------------------------------------------------------------------------
__global__ __launch_bounds__(256) void patch_embed(
    const float* __restrict__ img, const float* __restrict__ Wp,
    const float* __restrict__ bp, float* __restrict__ tokens)
{
  __shared__ float xs[588];
  const int bn = blockIdx.x;
  const int b = bn >> 8, n = bn & 255;
  const int i = n >> 4, j = n & 15;
  for (int k = threadIdx.x; k < 588; k += 256) {
    int c = k % 3;
    int t = k / 3;
    int pc = t % 14;
    int pr = t / 14;
    xs[k] = img[(((size_t)(b * 3 + c) * 224) + (i * 14 + pr)) * 224 + (j * 14 + pc)];
  }
  __syncthreads();
  const int d0 = threadIdx.x, d1 = threadIdx.x + 256;
  float a0 = 0.f, a1 = 0.f;
  for (int k = 0; k < 588; ++k) {
    float x = xs[k];
    a0 = fmaf(x, Wp[(size_t)k * 512 + d0], a0);
    a1 = fmaf(x, Wp[(size_t)k * 512 + d1], a1);
  }
  tokens[(size_t)bn * 512 + d0] = a0 + bp[d0];
  tokens[(size_t)bn * 512 + d1] = a1 + bp[d1];
}

// ---------------------------------------------------------------------------
__global__ __launch_bounds__(256) void init_lv_kernel(
    const float* __restrict__ initl, float* __restrict__ lv)
{
  int f = blockIdx.x * 256 + threadIdx.x;
  int d4 = f & 127;
  int l = (f >> 15) % 6;
  float4 v = *(const float4*)(initl + (size_t)l * 512 + d4 * 4);
  *(float4*)(lv + (size_t)f * 4) = v;
}

// ---------------------------------------------------------------------------
// Startup norms: invn[bl][n] = 1/max(||lv[bl,n,:]||, 1e-12). One-shot;
// steady-state values produced by combine3's fused wave-reduce.
// ---------------------------------------------------------------------------
__global__ __launch_bounds__(256) void norm0_k(
    const float* __restrict__ lv, float* __restrict__ invn)
{
  int bl = blockIdx.x;
  int n = threadIdx.x;
  const float* row = lv + ((size_t)bl * 256 + n) * 512;
  float ss = 0.f;
  for (int k = 0; k < 512; k += 4) {
    float4 v = *(const float4*)(row + k);
    ss = fmaf(v.x, v.x, ss);
    ss = fmaf(v.y, v.y, ss);
    ss = fmaf(v.z, v.z, ss);
    ss = fmaf(v.w, v.w, ss);
  }
  invn[(size_t)bl * 256 + n] = 1.0f / fmaxf(sqrtf(ss), 1e-12f);
}

// ---------------------------------------------------------------------------
// Pack weights fp32 [G][K][N] -> hi/lo bf16 fragment-image.
// ---------------------------------------------------------------------------
__global__ __launch_bounds__(256) void pack_w(
    const float* __restrict__ src, short* __restrict__ dst, int KT, int NT)
{
  int sidx = blockIdx.x * 256 + threadIdx.x;
  int slot = sidx & 511;
  int blk = sidx >> 9;
  int kt = blk % KT;
  int rest = blk / KT;
  int nt = rest % NT;
  int g = rest / NT;
  int f = slot >> 6, lane = slot & 63;
  int N = NT * 128, K = KT * 32;
  int n = nt * 128 + f * 16 + (lane & 15);
  int k0 = kt * 32 + (lane >> 4) * 8;
  const float* s = src + ((size_t)g * K + k0) * N + n;
  unsigned short hi[8], lo[8];
#pragma unroll
  for (int j = 0; j < 8; ++j) split2(s[(size_t)j * N], &hi[j], &lo[j]);
  short* d = dst + (size_t)blk * 8192 + slot * 8;
  *(int4*)d = pack8(hi);
  *(int4*)(d + 4096) = pack8(lo);
}

// ---------------------------------------------------------------------------
// Startup A-pack (steady-state fused into combine3).
// ---------------------------------------------------------------------------
__global__ __launch_bounds__(256) void pack_A(
    const float* __restrict__ lv, const float* __restrict__ pos,
    short* __restrict__ Abu, short* __restrict__ Atd)
{
  const int bx = blockIdx.x;              // 0..1279
  const int lg = bx >> 8, mt = (bx >> 4) & 15, kt = bx & 15;
  const size_t blk = (size_t)bx * 8192;
#pragma unroll
  for (int ss = 0; ss < 2; ++ss) {
    int s = threadIdx.x + ss * 256;
    int f = s >> 6, l = s & 63;
    int m = mt * 128 + (f << 4) + (l & 15);
    int b = m >> 8, n = m & 255;
    int d = kt * 32 + ((l >> 4) << 3);
    const float* pbu = lv + ((size_t)(b * L6 + lg) * 256 + n) * 512 + d;
    const float* ptd = lv + ((size_t)(b * L6 + lg + 1) * 256 + n) * 512 + d;
    const float* pp = pos + (size_t)n * 512 + d;
    float4 u0 = *(const float4*)pbu;
    float4 u1 = *(const float4*)(pbu + 4);
    float xv[8] = {u0.x, u0.y, u0.z, u0.w, u1.x, u1.y, u1.z, u1.w};
    unsigned short hi[8], lo[8];
#pragma unroll
    for (int j = 0; j < 8; ++j) split2(xv[j], &hi[j], &lo[j]);
    *(int4*)(Abu + blk + s * 8) = pack8(hi);
    *(int4*)(Abu + blk + 4096 + s * 8) = pack8(lo);
    float4 v0 = *(const float4*)ptd;
    float4 v1 = *(const float4*)(ptd + 4);
    float4 p0 = *(const float4*)pp;
    float4 p1 = *(const float4*)(pp + 4);
    float yv[8] = {v0.x + p0.x, v0.y + p0.y, v0.z + p0.z, v0.w + p0.w,
                   v1.x + p1.x, v1.y + p1.y, v1.z + p1.z, v1.w + p1.w};
#pragma unroll
    for (int j = 0; j < 8; ++j) split2(yv[j], &hi[j], &lo[j]);
    *(int4*)(Atd + blk + s * 8) = pack8(hi);
    *(int4*)(Atd + blk + 4096 + s * 8) = pack8(lo);
  }
}

// ---------------------------------------------------------------------------
// FF1 r10: flat GEMM + explicit per-wave software pipeline. Flat mode has no
// barriers, so the only serializer is the vmcnt wait on the last fragment
// load before each step's first MFMA (six prior structures all ~110us with
// every pipe <25% — latency-bound). Split each K-step into two j-phases and
// prefetch {A(kt+1), B-phase0(kt+1)} BETWEEN the MFMA phases so every wait
// lands after >=24 MFMAs of issued compute. Dual A-sets (even/odd kt) avoid
// register moves. Per-acc MFMA order (hh,lh,hl; kt ascending) unchanged ->
// bit-identical. Budget ~166 VGPR <= 168 cap (waves=3, same occupancy).
// ---------------------------------------------------------------------------
__global__ __launch_bounds__(256, 3) void ff1_k(
    const short* __restrict__ Wa, const short* __restrict__ Ap,
    const float* __restrict__ b1, short* __restrict__ hpk)
{
  const int per_x = gridDim.x >> 3;
  const int gid = (blockIdx.x & 7) * per_x + (blockIdx.x >> 3);
  const int tt = gid & 15;
  const int tile = gid >> 4;
  const int ht = tile & 15;
  const int z = tile >> 4;
  const int tid = threadIdx.x, lane = tid & 63, w = tid >> 6;
  const int wm = (w >> 1) * 64, wn = (w & 1) * 64;
  const short* ga = Wa + (size_t)(z * 16 + ht) * 16 * 8192 + (wm << 5) + lane * 8;
  const short* gb = Ap + (size_t)(z * 16 + tt) * 16 * 8192 + (wn << 5) + lane * 8;

  f32x4 acc[4][4];
#pragma unroll
  for (int i = 0; i < 4; ++i)
#pragma unroll
    for (int j = 0; j < 4; ++j) acc[i][j] = (f32x4)(0.0f);

  bf16x8 ahE[4], alE[4];   // A set, even kt
  bf16x8 ahO[4], alO[4];   // A set, odd kt
  bf16x8 bh0[2], bl0[2];   // B phase-0 (j 0..1) of current kt
  bf16x8 bh1[2], bl1[2];   // B phase-1 (j 2..3) of current kt

  // prologue: A(0), B(0,phase0)
#pragma unroll
  for (int i = 0; i < 4; ++i) {
    ahE[i] = *(const bf16x8*)(ga + i * 512);
    alE[i] = *(const bf16x8*)(ga + 4096 + i * 512);
  }
#pragma unroll
  for (int j = 0; j < 2; ++j) {
    bh0[j] = *(const bf16x8*)(gb + j * 512);
    bl0[j] = *(const bf16x8*)(gb + 4096 + j * 512);
  }

#define FF1_MFMA_PHASE(AH, AL, BH, BL, JB)                                    \
  do {                                                                        \
    _Pragma("unroll")                                                         \
    for (int j2 = 0; j2 < 2; ++j2)                                            \
      _Pragma("unroll")                                                       \
      for (int i = 0; i < 4; ++i)                                             \
        acc[i][(JB) + j2] = __builtin_amdgcn_mfma_f32_16x16x32_bf16(          \
            AH[i], BH[j2], acc[i][(JB) + j2], 0, 0, 0);                       \
    _Pragma("unroll")                                                         \
    for (int j2 = 0; j2 < 2; ++j2)                                            \
      _Pragma("unroll")                                                       \
      for (int i = 0; i < 4; ++i)                                             \
        acc[i][(JB) + j2] = __builtin_amdgcn_mfma_f32_16x16x32_bf16(          \
            AL[i], BH[j2], acc[i][(JB) + j2], 0, 0, 0);                       \
    _Pragma("unroll")                                                         \
    for (int j2 = 0; j2 < 2; ++j2)                                            \
      _Pragma("unroll")                                                       \
      for (int i = 0; i < 4; ++i)                                             \
        acc[i][(JB) + j2] = __builtin_amdgcn_mfma_f32_16x16x32_bf16(          \
            AH[i], BL[j2], acc[i][(JB) + j2], 0, 0, 0);                       \
  } while (0)

#pragma unroll
  for (int kt = 0; kt < 16; ++kt) {
    const short* pb = gb + (size_t)kt * 8192;
    const short* pa1 = ga + (size_t)(kt + 1) * 8192;
    const short* pb1 = gb + (size_t)(kt + 1) * 8192;
    const bool even = (kt & 1) == 0;
    // load B(kt, phase1)
#pragma unroll
    for (int j2 = 0; j2 < 2; ++j2) {
      bh1[j2] = *(const bf16x8*)(pb + (2 + j2) * 512);
      bl1[j2] = *(const bf16x8*)(pb + 4096 + (2 + j2) * 512);
    }
    // prefetch A(kt+1) into the alternate set
    if (kt < 15) {
#pragma unroll
      for (int i = 0; i < 4; ++i) {
        if (even) {
          ahO[i] = *(const bf16x8*)(pa1 + i * 512);
          alO[i] = *(const bf16x8*)(pa1 + 4096 + i * 512);
        } else {
          ahE[i] = *(const bf16x8*)(pa1 + i * 512);
          alE[i] = *(const bf16x8*)(pa1 + 4096 + i * 512);
        }
      }
    }
    // MFMA phase 0 (covers the B1/A-prefetch latency)
    if (even) FF1_MFMA_PHASE(ahE, alE, bh0, bl0, 0);
    else      FF1_MFMA_PHASE(ahO, alO, bh0, bl0, 0);
    // prefetch B(kt+1, phase0)
    if (kt < 15) {
#pragma unroll
      for (int j2 = 0; j2 < 2; ++j2) {
        bh0[j2] = *(const bf16x8*)(pb1 + j2 * 512);
        bl0[j2] = *(const bf16x8*)(pb1 + 4096 + j2 * 512);
      }
    }
    // MFMA phase 1 (covers the B0-prefetch latency)
    if (even) FF1_MFMA_PHASE(ahE, alE, bh1, bl1, 2);
    else      FF1_MFMA_PHASE(ahO, alO, bh1, bl1, 2);
  }
#undef FF1_MFMA_PHASE

  const int q = lane >> 4, t = lane & 15;
  const float* b1g = b1 + (size_t)z * 2048;
#pragma unroll
  for (int i = 0; i < 4; ++i) {
    int Hb = ht * 128 + wm + i * 16 + q * 4;
    float4 bv = *(const float4*)(b1g + Hb);
    float bb[4] = {bv.x, bv.y, bv.z, bv.w};
    int kt2 = Hb >> 5;
    int g2 = (Hb >> 3) & 3;
    int jb = Hb & 7;                       // 0 or 4
    size_t blkbase = ((size_t)(z * 16 + tt) * 64 + kt2) * 8192;
#pragma unroll
    for (int j = 0; j < 4; ++j) {
      int f2 = (wn >> 4) + j;
      size_t off = blkbase + (size_t)(f2 * 64 + g2 * 16 + t) * 8 + jb;
      unsigned short hi[4], lo[4];
#pragma unroll
      for (int r = 0; r < 4; ++r) {
        float x = gelu_exact(acc[i][j][r] + bb[r]);
        split2(x, &hi[r], &lo[r]);
      }
      *(uint2*)(hpk + off) =
          make_uint2((unsigned)hi[0] | ((unsigned)hi[1] << 16),
                     (unsigned)hi[2] | ((unsigned)hi[3] << 16));
      *(uint2*)(hpk + off + 4096) =
          make_uint2((unsigned)lo[0] | ((unsigned)lo[1] << 16),
                     (unsigned)lo[2] | ((unsigned)lo[3] << 16));
    }
  }
}

// ---------------------------------------------------------------------------
// Attention r7: MFMA Gram with norm table (best configuration).
// ---------------------------------------------------------------------------
__global__ __launch_bounds__(256, 3) void attn_k(
    const float* __restrict__ lv, const short* __restrict__ Apk,
    const float* __restrict__ invn, float* __restrict__ attnb)
{
  __shared__ __align__(16) short Bhi[8192];   // 16 frags x 64 lanes x 8
  __shared__ __align__(16) short Blo[8192];
  __shared__ float scL[256];
  __shared__ float red[32][4];
  const int a = blockIdx.x;
  const int s = a >> 3;
  const int b = a & 7;                 // batch == XCD group
  const int l = s >> 3;                // level 0..5
  const int bl = b * 6 + l;
  const int i0 = (s & 7) * 32;
  const float* base = lv + (size_t)bl * 131072;
  const int tid = threadIdx.x, lane = tid & 63, w = tid >> 6;
  const int q = lane >> 4, c = lane & 15;

  scL[tid] = invn[(size_t)bl * 256 + tid];   // one row scale per thread

  f32x4 acc[2][4];
#pragma unroll
  for (int i = 0; i < 2; ++i)
#pragma unroll
    for (int j = 0; j < 4; ++j) acc[i][j] = (f32x4)(0.0f);

  // Apk bu-image sub-blocks for this (b,l): tokens n 0..127 -> tile 2b,
  // n 128..255 -> tile 2b+1. Valid only for l<5.
  const short* src0 = Apk + ((size_t)(l * 16 + 2 * b) * 16) * 8192;
  const short* src1 = Apk + ((size_t)(l * 16 + 2 * b + 1) * 16) * 8192;

  for (int kt = 0; kt < 16; ++kt) {
    __syncthreads();                    // prev step's LDS reads done
    if (l < 5) {
      const char* p0 = (const char*)(src0 + (size_t)kt * 8192);
      const char* p1 = (const char*)(src1 + (size_t)kt * 8192);
      gload16(p0 + tid * 16,         (char*)Bhi + tid * 16);
      gload16(p0 + 4096 + tid * 16,  (char*)Bhi + 4096 + tid * 16);
      gload16(p0 + 8192 + tid * 16,  (char*)Blo + tid * 16);
      gload16(p0 + 12288 + tid * 16, (char*)Blo + 4096 + tid * 16);
      gload16(p1 + tid * 16,         (char*)Bhi + 8192 + tid * 16);
      gload16(p1 + 4096 + tid * 16,  (char*)Bhi + 12288 + tid * 16);
      gload16(p1 + 8192 + tid * 16,  (char*)Blo + 8192 + tid * 16);
      gload16(p1 + 12288 + tid * 16, (char*)Blo + 12288 + tid * 16);
    } else {
      const int k0 = kt * 32;
#pragma unroll
      for (int it = 0; it < 8; ++it) {
        int f = it * 256 + tid;
        int j = f >> 3, c4 = f & 7;
        float4 v = *(const float4*)(base + (size_t)j * 512 + k0 + c4 * 4);
        unsigned short hi[4], lo[4];
        split2(v.x, &hi[0], &lo[0]);
        split2(v.y, &hi[1], &lo[1]);
        split2(v.z, &hi[2], &lo[2]);
        split2(v.w, &hi[3], &lo[3]);
        int fg = j >> 4;
        int la = (c4 >> 1) * 16 + (j & 15);
        int half = (c4 & 1) * 4;
        *(uint2*)&Bhi[fg * 512 + la * 8 + half] =
            make_uint2((unsigned)hi[0] | ((unsigned)hi[1] << 16),
                       (unsigned)hi[2] | ((unsigned)hi[3] << 16));
        *(uint2*)&Blo[fg * 512 + la * 8 + half] =
            make_uint2((unsigned)lo[0] | ((unsigned)lo[1] << 16),
                       (unsigned)lo[2] | ((unsigned)lo[3] << 16));
      }
    }
    __syncthreads();                    // staging complete
    bf16x8 ah[2], al[2], bh[4], blv[4];
#pragma unroll
    for (int i = 0; i < 2; ++i) {
      int fg = (i0 >> 4) + i;
      ah[i] = *(const bf16x8*)&Bhi[fg * 512 + lane * 8];
      al[i] = *(const bf16x8*)&Blo[fg * 512 + lane * 8];
    }
#pragma unroll
    for (int j = 0; j < 4; ++j) {
      int fg = w * 4 + j;
      bh[j] = *(const bf16x8*)&Bhi[fg * 512 + lane * 8];
      blv[j] = *(const bf16x8*)&Blo[fg * 512 + lane * 8];
    }
#pragma unroll
    for (int j = 0; j < 4; ++j)
#pragma unroll
      for (int i = 0; i < 2; ++i)
        acc[i][j] = __builtin_amdgcn_mfma_f32_16x16x32_bf16(
            ah[i], bh[j], acc[i][j], 0, 0, 0);
#pragma unroll
    for (int j = 0; j < 4; ++j)
#pragma unroll
      for (int i = 0; i < 2; ++i)
        acc[i][j] = __builtin_amdgcn_mfma_f32_16x16x32_bf16(
            al[i], bh[j], acc[i][j], 0, 0, 0);
#pragma unroll
    for (int j = 0; j < 4; ++j)
#pragma unroll
      for (int i = 0; i < 2; ++i)
        acc[i][j] = __builtin_amdgcn_mfma_f32_16x16x32_bf16(
            ah[i], blv[j], acc[i][j], 0, 0, 0);
  }
  __syncthreads();                      // scL writes visible (also from loop)

  const float rs = 0.04419417382415922f;  // 512^-0.5
  // scale + diag; value at (ai,bj,r): i = i0+ai*16+q*4+r, j = w*64+bj*16+c
#pragma unroll
  for (int ai = 0; ai < 2; ++ai)
#pragma unroll
    for (int bj = 0; bj < 4; ++bj)
#pragma unroll
      for (int r = 0; r < 4; ++r) {
        int i = i0 + ai * 16 + q * 4 + r;
        int j = w * 64 + bj * 16 + c;
        float sv = acc[ai][bj][r] * scL[j] * rs;
        if (j == i) sv = -0.0005f;
        acc[ai][bj][r] = sv;
      }
  // wave-local row max (over this wave's 64 j), then cross-wave via red
  float mx[2][4];
#pragma unroll
  for (int ai = 0; ai < 2; ++ai)
#pragma unroll
    for (int r = 0; r < 4; ++r) {
      float m = fmaxf(fmaxf(acc[ai][0][r], acc[ai][1][r]),
                      fmaxf(acc[ai][2][r], acc[ai][3][r]));
      m = fmaxf(m, __shfl_xor(m, 1));
      m = fmaxf(m, __shfl_xor(m, 2));
      m = fmaxf(m, __shfl_xor(m, 4));
      m = fmaxf(m, __shfl_xor(m, 8));
      mx[ai][r] = m;
    }
  if (c == 0) {
#pragma unroll
    for (int ai = 0; ai < 2; ++ai)
#pragma unroll
      for (int r = 0; r < 4; ++r) red[ai * 16 + q * 4 + r][w] = mx[ai][r];
  }
  __syncthreads();
#pragma unroll
  for (int ai = 0; ai < 2; ++ai)
#pragma unroll
    for (int r = 0; r < 4; ++r) {
      int row = ai * 16 + q * 4 + r;
      mx[ai][r] = fmaxf(fmaxf(red[row][0], red[row][1]),
                        fmaxf(red[row][2], red[row][3]));
    }
  __syncthreads();                      // before red reuse for sums
  float sm[2][4];
#pragma unroll
  for (int ai = 0; ai < 2; ++ai)
#pragma unroll
    for (int r = 0; r < 4; ++r) {
      float t = 0.f;
#pragma unroll
      for (int bj = 0; bj < 4; ++bj) {
        float e = expf(acc[ai][bj][r] - mx[ai][r]);
        acc[ai][bj][r] = e;
        t += e;
      }
      t += __shfl_xor(t, 1);
      t += __shfl_xor(t, 2);
      t += __shfl_xor(t, 4);
      t += __shfl_xor(t, 8);
      sm[ai][r] = t;
    }
  if (c == 0) {
#pragma unroll
    for (int ai = 0; ai < 2; ++ai)
#pragma unroll
      for (int r = 0; r < 4; ++r) red[ai * 16 + q * 4 + r][w] = sm[ai][r];
  }
  __syncthreads();
  float* ob = attnb + (size_t)bl * 65536;
#pragma unroll
  for (int ai = 0; ai < 2; ++ai)
#pragma unroll
    for (int r = 0; r < 4; ++r) {
      int row = ai * 16 + q * 4 + r;
      float S = red[row][0] + red[row][1] + red[row][2] + red[row][3];
      float inv = 1.0f / S;
      int i = i0 + row;
#pragma unroll
      for (int bj = 0; bj < 4; ++bj) {
        int j = w * 64 + bj * 16 + c;
        ob[(size_t)i * 256 + j] = acc[ai][bj][r] * inv;
      }
    }
}

// ---------------------------------------------------------------------------
// Consensus: accum += attnb @ lv (pure RMW). Grid 768, XCD-grouped by bl.
// ---------------------------------------------------------------------------
__global__ __launch_bounds__(256) void cons_k(
    const float* __restrict__ attnb, const float* __restrict__ lv,
    float* __restrict__ accum)
{
  __shared__ __align__(16) char smemraw[25088];
  const int a = blockIdx.x;
  const int s = a >> 3;
  const int bl = (a & 7) * 6 + (s >> 4);
  const int tile = s & 15;
  int it0 = (tile >> 2) * 64;
  int dt0 = (tile & 3) * 128;
  const float* A = attnb + (size_t)bl * 65536;
  const float* Bm = lv + (size_t)bl * 131072;
  float (*Ast)[68] = (float(*)[68])smemraw;
  float (*Bs)[128] = (float(*)[128])(smemraw + 8704);
  const int tid = threadIdx.x;
  const int ty = tid >> 4, tx = tid & 15;
  float acc[4][8];
#pragma unroll
  for (int i = 0; i < 4; ++i)
#pragma unroll
    for (int j = 0; j < 8; ++j) acc[i][j] = 0.f;

  for (int k0 = 0; k0 < 256; k0 += 32) {
#pragma unroll
    for (int it = 0; it < 2; ++it) {
      int f = it * 256 + tid;
      int r = f >> 3, c4 = f & 7;
      float4 v = *(const float4*)(A + (size_t)(it0 + r) * 256 + k0 + c4 * 4);
      Ast[c4 * 4 + 0][r] = v.x;
      Ast[c4 * 4 + 1][r] = v.y;
      Ast[c4 * 4 + 2][r] = v.z;
      Ast[c4 * 4 + 3][r] = v.w;
    }
#pragma unroll
    for (int it = 0; it < 4; ++it) {
      int kr = (tid >> 5) + it * 8;
      int c4 = tid & 31;
      *(float4*)&Bs[kr][c4 * 4] =
          *(const float4*)(Bm + (size_t)(k0 + kr) * 512 + dt0 + c4 * 4);
    }
    __syncthreads();
#pragma unroll 8
    for (int k = 0; k < 32; ++k) {
      float4 av = *(const float4*)&Ast[k][ty * 4];
      float4 b0 = *(const float4*)&Bs[k][tx * 4];
      float4 b1 = *(const float4*)&Bs[k][64 + tx * 4];
      float avv[4] = {av.x, av.y, av.z, av.w};
      float bv[8] = {b0.x, b0.y, b0.z, b0.w, b1.x, b1.y, b1.z, b1.w};
#pragma unroll
      for (int i = 0; i < 4; ++i)
#pragma unroll
        for (int j = 0; j < 8; ++j)
          acc[i][j] = fmaf(avv[i], bv[j], acc[i][j]);
    }
    __syncthreads();
  }
#pragma unroll
  for (int ii = 0; ii < 4; ++ii) {
    int i = it0 + ty * 4 + ii;
    float* arow = accum + (size_t)bl * 131072 + (size_t)i * 512 + dt0;
#pragma unroll
    for (int j = 0; j < 4; ++j) arow[tx * 4 + j] += acc[ii][j];
#pragma unroll
    for (int j = 0; j < 4; ++j) arow[64 + tx * 4 + j] += acc[ii][4 + j];
  }
}

// ---------------------------------------------------------------------------
// FF2: 64(token) x 128(outd) block, 640 blocks, single-buf LDS 24KB.
// r2-proven LDS-staged version. r8's flat conversion REGRESSED (tail 130us):
// the 40MB hpk A-stream thrashes the 4MB/XCD L2, evicting the shared W2
// B-panel. Keep LDS-staged.
//  emode 0 (bu):      accum = lv + v            (store, levels 1..5)
//  emode 1 (td):      l==0: accum=lv+tokens+v;  else accum += v
// ---------------------------------------------------------------------------
__global__ __launch_bounds__(256, 4) void mfma_ff2(
    const short* __restrict__ hpk, const short* __restrict__ Wb,
    const float* __restrict__ b2, const float* __restrict__ lv,
    const float* __restrict__ tokens, float* __restrict__ accum,
    int olvbase, int emode)
{
  const int per_x = gridDim.x >> 3;
  const int gid = (blockIdx.x & 7) * per_x + (blockIdx.x >> 3);
  const int nt2 = gid & 3;
  const int tile = gid >> 2;
  const int mt2 = tile & 31;          // 64-token tiles
  const int z = tile >> 5;

  __shared__ __align__(16) short SA[4096];   // hi 2048 | lo 2048
  __shared__ __align__(16) short SB[8192];   // hi 4096 | lo 4096
  const int tid = threadIdx.x, lane = tid & 63, w = tid >> 6;
  const int wm = (w >> 1) * 32, wn = (w & 1) * 64;
  const short* gaBase = hpk + (size_t)(z * 16 + (mt2 >> 1)) * 64 * 8192
                        + (size_t)(mt2 & 1) * 2048;
  const short* gb = Wb + (size_t)(z * 4 + nt2) * 64 * 8192;

  f32x4 acc[2][4];
#pragma unroll
  for (int i = 0; i < 2; ++i)
#pragma unroll
    for (int j = 0; j < 4; ++j) acc[i][j] = (f32x4)(0.0f);

  for (int kt = 0; kt < 64; ++kt) {
    __syncthreads();
    const char* pa = (const char*)(gaBase + (size_t)kt * 8192);
    const char* pb = (const char*)(gb + (size_t)kt * 8192);
    gload16(pa + w * 1024 + lane * 16, (char*)SA + w * 1024);
    gload16(pa + 8192 + w * 1024 + lane * 16, (char*)SA + 4096 + w * 1024);
#pragma unroll
    for (int c = 0; c < 4; ++c)
      gload16(pb + w * 4096 + c * 1024 + lane * 16,
              (char*)SB + w * 4096 + c * 1024);
    __syncthreads();
    bf16x8 ah[2], al[2];
#pragma unroll
    for (int i = 0; i < 2; ++i) {
      int f = (wm >> 4) + i;
      ah[i] = *(const bf16x8*)&SA[f * 512 + lane * 8];
      al[i] = *(const bf16x8*)&SA[2048 + f * 512 + lane * 8];
    }
#pragma unroll
    for (int jp = 0; jp < 2; ++jp) {
      bf16x8 bh[2], bl[2];
#pragma unroll
      for (int j2 = 0; j2 < 2; ++j2) {
        int f = (wn >> 4) + jp * 2 + j2;
        bh[j2] = *(const bf16x8*)&SB[f * 512 + lane * 8];
        bl[j2] = *(const bf16x8*)&SB[4096 + f * 512 + lane * 8];
      }
#pragma unroll
      for (int j2 = 0; j2 < 2; ++j2)
#pragma unroll
        for (int i = 0; i < 2; ++i)
          acc[i][jp * 2 + j2] = __builtin_amdgcn_mfma_f32_16x16x32_bf16(
              ah[i], bh[j2], acc[i][jp * 2 + j2], 0, 0, 0);
#pragma unroll
      for (int j2 = 0; j2 < 2; ++j2)
#pragma unroll
        for (int i = 0; i < 2; ++i)
          acc[i][jp * 2 + j2] = __builtin_amdgcn_mfma_f32_16x16x32_bf16(
              al[i], bh[j2], acc[i][jp * 2 + j2], 0, 0, 0);
#pragma unroll
      for (int j2 = 0; j2 < 2; ++j2)
#pragma unroll
        for (int i = 0; i < 2; ++i)
          acc[i][jp * 2 + j2] = __builtin_amdgcn_mfma_f32_16x16x32_bf16(
              ah[i], bl[j2], acc[i][jp * 2 + j2], 0, 0, 0);
    }
  }

  const int q = lane >> 4, t = lane & 15;
  const float* b2g = b2 + (size_t)z * 512;
  const int level = olvbase + z;
#pragma unroll
  for (int i = 0; i < 2; ++i) {
#pragma unroll
    for (int r = 0; r < 4; ++r) {
      int m = mt2 * 64 + wm + i * 16 + q * 4 + r;
      int b = m >> 8, n = m & 255;
      size_t rowoff = ((size_t)(b * L6 + level) * 256 + n) * 512;
      float* arow = accum + rowoff;
      const float* lrow = lv + rowoff;
      const float* trow = tokens + (size_t)m * 512;
#pragma unroll
      for (int j = 0; j < 4; ++j) {
        int col = nt2 * 128 + wn + j * 16 + t;
        float v = acc[i][j][r] + b2g[col];
        if (emode == 0)                       arow[col] = lrow[col] + v;
        else if (level == 0)                  arow[col] = lrow[col] + trow[col] + v;
        else                                  arow[col] += v;
      }
    }
  }
}

// ---------------------------------------------------------------------------
// combine3: lv = accum/contrib, write dout on last iter, fused next-iter
// A-packing, and fused exact-fp32 row-norm via 64-lane butterfly.
// ---------------------------------------------------------------------------
__global__ __launch_bounds__(256) void combine3(
    const float* __restrict__ accum, const float* __restrict__ pos,
    float* __restrict__ lv_out, short* __restrict__ Abu,
    short* __restrict__ Atd, float* __restrict__ invn,
    float* __restrict__ dout, int last)
{
  int t = blockIdx.x * 256 + threadIdx.x;   // 786,432 total
  int d8 = t & 63;
  int n = (t >> 6) & 255;
  int v = t >> 14;                          // b*6 + l, 0..47
  int l = v % 6, b = v / 6;
  int bn = (b << 8) | n;
  size_t idx = ((size_t)v * 256 + n) * 512 + d8 * 8;
  float4 a0 = *(const float4*)(accum + idx);
  float4 a1 = *(const float4*)(accum + idx + 4);
  float sc = (l == 5) ? (1.0f / 3.0f) : 0.25f;
  float r[8];
  r[0] = a0.x * sc; r[1] = a0.y * sc; r[2] = a0.z * sc; r[3] = a0.w * sc;
  r[4] = a1.x * sc; r[5] = a1.y * sc; r[6] = a1.z * sc; r[7] = a1.w * sc;
  *(float4*)(lv_out + idx) = make_float4(r[0], r[1], r[2], r[3]);
  *(float4*)(lv_out + idx + 4) = make_float4(r[4], r[5], r[6], r[7]);
  if (last) {
    float* dp = dout + ((size_t)bn * 6 + l) * 512 + d8 * 8;
    *(float4*)dp = make_float4(r[0], r[1], r[2], r[3]);
    *(float4*)(dp + 4) = make_float4(r[4], r[5], r[6], r[7]);
  }
  // fused row norm: wave == one (v,n) row (d8 = lane)
  {
    float s8 = 0.f;
#pragma unroll
    for (int j = 0; j < 8; ++j) s8 = fmaf(r[j], r[j], s8);
#pragma unroll
    for (int o = 1; o < 64; o <<= 1) s8 += __shfl_xor(s8, o);
    if (d8 == 0) invn[(size_t)v * 256 + n] = 1.0f / fmaxf(sqrtf(s8), 1e-12f);
  }
  int m = bn;
  int mt = m >> 7;
  int kt = d8 >> 2;
  int s = (((m & 127) >> 4) << 6) | (((d8 & 3) << 4) | (m & 15));
  unsigned short hi[8], lo[8];
  if (l < 5) {
    size_t blk = ((size_t)(l * 16 + mt) * 16 + kt) * 8192;
#pragma unroll
    for (int j = 0; j < 8; ++j) split2(r[j], &hi[j], &lo[j]);
    *(int4*)(Abu + blk + s * 8) = pack8(hi);
    *(int4*)(Abu + blk + 4096 + s * 8) = pack8(lo);
  }
  if (l >= 1) {
    const float* pp = pos + (size_t)n * 512 + d8 * 8;
    float4 p0 = *(const float4*)pp;
    float4 p1 = *(const float4*)(pp + 4);
    float y[8] = {r[0] + p0.x, r[1] + p0.y, r[2] + p0.z, r[3] + p0.w,
                  r[4] + p1.x, r[5] + p1.y, r[6] + p1.z, r[7] + p1.w};
    size_t blk = ((size_t)((l - 1) * 16 + mt) * 16 + kt) * 8192;
#pragma unroll
    for (int j = 0; j < 8; ++j) split2(y[j], &hi[j], &lo[j]);
    *(int4*)(Atd + blk + s * 8) = pack8(hi);
    *(int4*)(Atd + blk + 4096 + s * 8) = pack8(lo);
  }
}

// ---------------------------------------------------------------------------
extern "C" void kernel_launch(void* const* d_in, const int* in_sizes, int n_in,
                              void* d_out, int out_size, void* d_ws, size_t ws_size,
                              hipStream_t stream)
{
  const float* img   = (const float*)d_in[0];
  const float* Wp    = (const float*)d_in[1];
  const float* bp    = (const float*)d_in[2];
  const float* pos   = (const float*)d_in[3];
  const float* initl = (const float*)d_in[4];
  const float* buW1  = (const float*)d_in[5];
  const float* bub1  = (const float*)d_in[6];
  const float* buW2  = (const float*)d_in[7];
  const float* bub2  = (const float*)d_in[8];
  const float* tdW1  = (const float*)d_in[9];
  const float* tdb1  = (const float*)d_in[10];
  const float* tdW2  = (const float*)d_in[11];
  const float* tdb2  = (const float*)d_in[12];

  float* ws = (float*)d_ws;
  const size_t LV = (size_t)8 * 6 * 256 * 512;   // 6,291,456 floats
  float* lv     = ws;
  float* tokens = lv + LV;                        // 1,048,576
  float* accum  = tokens + 1048576ull;            // 6,291,456
  short* W1all  = (short*)(accum + LV);           // 20,971,520 shorts
  short* W2all  = W1all + 20971520ull;            // 20,971,520 shorts
  short* Apk    = W2all + 20971520ull;            // 20,971,520 shorts
  short* hall   = Apk + 20971520ull;              // 41,943,040 shorts (5z hi/lo)
  float* invn   = (float*)(hall + 41943040ull);   // 48*256 f32 = 49,152 B
  // total = 264,241,152 + 49,152 = 264,290,304 B == proven capacity

  // attnb aliases hall's upper half (12.6 MB needed, 42 MB available);
  // it lives only between attn_k and cons_k, and hall is rewritten by the
  // NEXT iteration's ff1 passes after cons_k has consumed it.
  float* attnb = (float*)(hall + 20971520ull);
  float* dout  = (float*)d_out;

  pack_w<<<2560, 256, 0, stream>>>(buW1, W1all, 16, 16);
  pack_w<<<2560, 256, 0, stream>>>(tdW1, W1all + 5 * SH_W_GRP, 16, 16);
  pack_w<<<2560, 256, 0, stream>>>(buW2, W2all, 64, 4);
  pack_w<<<2560, 256, 0, stream>>>(tdW2, W2all + 5 * SH_W_GRP, 64, 4);

  patch_embed<<<2048, 256, 0, stream>>>(img, Wp, bp, tokens);
  init_lv_kernel<<<6144, 256, 0, stream>>>(initl, lv);
  norm0_k<<<48, 256, 0, stream>>>(lv, invn);
  pack_A<<<1280, 256, 0, stream>>>(lv, pos, Apk, Apk + SH_A_TDOFF);

  for (int it = 0; it < 12; ++it) {
    // K1: ff1-bu (fills hall)
    ff1_k<<<1280, 256, 0, stream>>>(W1all, Apk, bub1, hall);
    // K2: ff2-bu emode0 (store accum = lv + v, levels 1..5)
    mfma_ff2<<<640, 256, 0, stream>>>(hall, W2all, bub2, lv, tokens, accum, 1, 0);
    // K3: ff1-td (refills hall)
    ff1_k<<<1280, 256, 0, stream>>>(W1all + 5 * SH_W_GRP, Apk + SH_A_TDOFF,
                                    tdb1, hall);
    // K4: ff2-td emode1 (level0 store lv+tokens+v; levels 1..4 RMW)
    mfma_ff2<<<640, 256, 0, stream>>>(hall, W2all + 5 * SH_W_GRP, tdb2, lv,
                                      tokens, accum, 0, 1);
    // K5: MFMA attention (reads Apk bu-image + invn; lv only for level 5)
    attn_k<<<384, 256, 0, stream>>>(lv, Apk, invn, attnb);
    // K6: consensus RMW into accum
    cons_k<<<768, 256, 0, stream>>>(attnb, lv, accum);
    // K7: combine + dout + next-iter A-pack + fused norms
    combine3<<<3072, 256, 0, stream>>>(accum, pos, lv, Apk, Apk + SH_A_TDOFF,
                                       invn, dout, it == 11 ? 1 : 0);
  }
}